// Round 1
// 331.666 us; speedup vs baseline: 1.0327x; 1.0327x over previous
//
#include <hip/hip_runtime.h>
#include <stdint.h>

#define SEQ    2048
#define NB     2
#define DMODEL 1024
#define NHEAD  16
#define HDIM   64
#define FFDIM  4096
#define WIN    128
#define MTOK   (NB*SEQ)   // 4096 tokens

typedef short short8 __attribute__((ext_vector_type(8)));  // 8 bf16 (4 VGPRs)
typedef float f32x4  __attribute__((ext_vector_type(4)));

__device__ __forceinline__ float bf2f(uint16_t h){ return __uint_as_float(((uint32_t)h) << 16); }
__device__ __forceinline__ uint16_t f2bf(float f){           // RNE f32->bf16
  uint32_t u = __float_as_uint(f);
  u += 0x7fffu + ((u >> 16) & 1u);
  return (uint16_t)(u >> 16);
}

// tanh-form GELU, branch-free; max |delta| vs exact erf-GELU ~3e-3.
__device__ __forceinline__ float gelu_f(float v){
  float u = 0.7978845608028654f * v * (1.0f + 0.044715f * v * v);
  u = fminf(fmaxf(u, -10.0f), 10.0f);
  const float e = __expf(2.0f * u);
  const float th = (e - 1.0f) / (e + 1.0f);
  return 0.5f * v * (1.0f + th);
}

__device__ __forceinline__ void gl_lds16(const void* g, void* l) {
  __builtin_amdgcn_global_load_lds((const __attribute__((address_space(1))) void*)g,
                                   (__attribute__((address_space(3))) void*)l, 16, 0, 0);
}

// raw workgroup barrier WITHOUT the __syncthreads() vmcnt(0) drain.
// asm memory fences pin C++ LDS/global ops on each side.
__device__ __forceinline__ void BAR() {
  asm volatile("" ::: "memory");
  __builtin_amdgcn_s_barrier();
  asm volatile("" ::: "memory");
}

// ---- fused: weights fp32->bf16 (blocks 0..12287) + LN1 (blocks 12288..16383)
__global__ __launch_bounds__(256) void cvtln_kernel(
    const float* __restrict__ s0, const float* __restrict__ s1,
    const float* __restrict__ s2, const float* __restrict__ s3,
    uint16_t* __restrict__ d0, uint16_t* __restrict__ d1,
    uint16_t* __restrict__ d2, uint16_t* __restrict__ d3,
    const float* __restrict__ x, const float* __restrict__ g,
    const float* __restrict__ b, uint16_t* __restrict__ y)
{
  __shared__ float red[8];
  const int t = threadIdx.x;
  if (blockIdx.x < 12288) {
    size_t i = (size_t)blockIdx.x * 256 + t;   // float4 index; 3,145,728 total
    const float* s; uint16_t* d; size_t off;
    if      (i <  768*1024) { s = s0; d = d0; off = i; }
    else if (i < 1024*1024) { s = s1; d = d1; off = i -  768*1024; }
    else if (i < 2048*1024) { s = s2; d = d2; off = i - 1024*1024; }
    else                    { s = s3; d = d3; off = i - 2048*1024; }
    const float4 v = ((const float4*)s)[off];
    uint2 o;
    o.x = (uint32_t)f2bf(v.x) | ((uint32_t)f2bf(v.y) << 16);
    o.y = (uint32_t)f2bf(v.z) | ((uint32_t)f2bf(v.w) << 16);
    ((uint2*)d)[off] = o;
  } else {
    const int row = blockIdx.x - 12288;
    const float4 v = ((const float4*)(x + (size_t)row * DMODEL))[t];
    float s1 = v.x + v.y + v.z + v.w;
    float s2 = v.x*v.x + v.y*v.y + v.z*v.z + v.w*v.w;
    #pragma unroll
    for (int off = 32; off; off >>= 1) { s1 += __shfl_xor(s1, off, 64); s2 += __shfl_xor(s2, off, 64); }
    const int w = t >> 6;
    if ((t & 63) == 0) { red[w] = s1; red[4+w] = s2; }
    __syncthreads();
    s1 = red[0]+red[1]+red[2]+red[3];
    s2 = red[4]+red[5]+red[6]+red[7];
    const float mu = s1 * (1.0f/DMODEL);
    const float var = s2 * (1.0f/DMODEL) - mu*mu;
    const float rs = rsqrtf(var + 1e-5f);
    const float4 gv = ((const float4*)g)[t];
    const float4 bv = ((const float4*)b)[t];
    uint2 o;
    o.x = (uint32_t)f2bf((v.x-mu)*rs*gv.x + bv.x) | ((uint32_t)f2bf((v.y-mu)*rs*gv.y + bv.y) << 16);
    o.y = (uint32_t)f2bf((v.z-mu)*rs*gv.z + bv.z) | ((uint32_t)f2bf((v.w-mu)*rs*gv.w + bv.w) << 16);
    ((uint2*)(y + (size_t)row * DMODEL))[t] = o;
  }
}

// -------- LayerNorm: fp32 in -> bf16 out; one row (1024) per block ---------
__global__ __launch_bounds__(256) void ln_kernel(const float* __restrict__ x,
                                                 const float* __restrict__ g,
                                                 const float* __restrict__ b,
                                                 uint16_t* __restrict__ y)
{
  const int row = blockIdx.x;
  const int t = threadIdx.x;
  const float4 v = ((const float4*)(x + (size_t)row * DMODEL))[t];
  float s1 = v.x + v.y + v.z + v.w;
  float s2 = v.x*v.x + v.y*v.y + v.z*v.z + v.w*v.w;
  #pragma unroll
  for (int off = 32; off; off >>= 1) { s1 += __shfl_xor(s1, off, 64); s2 += __shfl_xor(s2, off, 64); }
  __shared__ float red[8];
  const int w = t >> 6;
  if ((t & 63) == 0) { red[w] = s1; red[4+w] = s2; }
  __syncthreads();
  s1 = red[0]+red[1]+red[2]+red[3];
  s2 = red[4]+red[5]+red[6]+red[7];
  const float mu = s1 * (1.0f/DMODEL);
  const float var = s2 * (1.0f/DMODEL) - mu*mu;
  const float rs = rsqrtf(var + 1e-5f);
  const float4 gv = ((const float4*)g)[t];
  const float4 bv = ((const float4*)b)[t];
  uint2 o;
  o.x = (uint32_t)f2bf((v.x-mu)*rs*gv.x + bv.x) | ((uint32_t)f2bf((v.y-mu)*rs*gv.y + bv.y) << 16);
  o.y = (uint32_t)f2bf((v.z-mu)*rs*gv.z + bv.z) | ((uint32_t)f2bf((v.w-mu)*rs*gv.w + bv.w) << 16);
  ((uint2*)(y + (size_t)row * DMODEL))[t] = o;
}

// ============ 256x256 deep-pipelined GEMM: C = A @ Bm^T (bf16 out) =========
// BK=32, 4-buffer LDS ring (128 KB), 512 thr / 8 waves (2M x 4N), per wave
// 128x64 output. 2 phases per K-tile, 16 MFMA + 2 global_load_lds per phase,
// counted vmcnt(8) once per K-tile (never drains in steady state), raw
// s_barrier (no __syncthreads -> no vmcnt(0) drain), setprio(1) around MFMA.
// Race safety: stage of tile t+3 writes ring slot (t-1)%4, whose reads all
// completed before the barrier that opened iteration t; vmcnt(8)+barrier
// collectively guarantees tile t+1 landed (tiles t+2,t+3 = newest 8 loads of
// every wave). LDS swizzle: physical 16B chunk = kq ^ ((row>>1)&3), applied
// by pre-swizzling the per-lane GLOBAL source (LDS dest stays linear for
// global_load_lds); 16-lane read groups then cover all 8 bank-groups twice
// -> 2-way = free. Requires K % 32 == 0 and K >= 96; M,N % 256 == 0.
// EPI: 0 = none, 2 = bias + GELU.
template<int EPI>
__global__ __launch_bounds__(512, 2) void gemm256(
    const uint16_t* __restrict__ A, const uint16_t* __restrict__ Bm,
    const float* __restrict__ bias, uint16_t* __restrict__ C,
    int M, int N, int K)
{
  __shared__ __align__(16) uint16_t L[4 * 16384];   // 128 KB
  const int t = threadIdx.x;
  const int l = t & 63;
  const int w = t >> 6;
  const int wm = w >> 2, wn = w & 3;                // 2 x 4 wave grid
  const int row0 = blockIdx.y * 256, col0 = blockIdx.x * 256;
  const int mrow = l & 15, kq = l >> 4;
  const int nt = K >> 5;                            // K-tiles of 32

  f32x4 acc[8][4];
  #pragma unroll
  for (int i = 0; i < 8; ++i)
    #pragma unroll
    for (int j = 0; j < 4; ++j)
      #pragma unroll
      for (int e = 0; e < 4; ++e) acc[i][j][e] = 0.0f;

  // staging: thread t owns LDS 16B slot t within each 8KB half (linear, as
  // global_load_lds requires); the k-chunk it fetches is the swizzled one.
  const int sr = t >> 2;                            // row-in-half 0..127
  const int kl = (t & 3) ^ ((t >> 3) & 3);          // logical k-chunk 0..3
  const uint16_t* aG = A  + (size_t)(row0 + sr) * K + kl * 8;
  const uint16_t* bG = Bm + (size_t)(col0 + sr) * K + kl * 8;
  char* const lds = (char*)L;
  const int soff = t * 16;

  #define STAGE_A(tt_) { char* d_ = lds + ((tt_) & 3) * 32768 + soff; \
      gl_lds16(aG + (tt_) * 32, d_); \
      gl_lds16(aG + (size_t)128 * K + (tt_) * 32, d_ + 8192); }
  #define STAGE_B(tt_) { char* d_ = lds + ((tt_) & 3) * 32768 + 16384 + soff; \
      gl_lds16(bG + (tt_) * 32, d_); \
      gl_lds16(bG + (size_t)128 * K + (tt_) * 32, d_ + 8192); }

  // prologue: tiles 0,1,2 in flight; wait oldest 4 (tile 0) -> vmcnt(8)
  STAGE_A(0); STAGE_B(0);
  STAGE_A(1); STAGE_B(1);
  STAGE_A(2); STAGE_B(2);
  asm volatile("s_waitcnt vmcnt(8)" ::: "memory");
  BAR();

  const int cphys = (kq ^ ((mrow >> 1) & 3)) << 4;  // physical chunk byte off

  for (int tt = 0; tt < nt; ++tt) {
    char* const bufA = lds + (tt & 3) * 32768;
    char* const bufB = bufA + 16384;
    // ---------------- phase A: mi 0..3 x ni 0..3 ----------------
    short8 bf[4], af[4];
    #pragma unroll
    for (int ni = 0; ni < 4; ++ni)
      bf[ni] = *(const short8*)(bufB + (wn*64 + ni*16 + mrow) * 64 + cphys);
    #pragma unroll
    for (int mi = 0; mi < 4; ++mi)
      af[mi] = *(const short8*)(bufA + (wm*128 + mi*16 + mrow) * 64 + cphys);
    if (tt + 3 < nt) STAGE_A(tt + 3);
    BAR();
    __builtin_amdgcn_s_setprio(1);
    #pragma unroll
    for (int mi = 0; mi < 4; ++mi)
      #pragma unroll
      for (int ni = 0; ni < 4; ++ni)
        acc[mi][ni] = __builtin_amdgcn_mfma_f32_16x16x32_bf16(af[mi], bf[ni], acc[mi][ni], 0, 0, 0);
    __builtin_amdgcn_s_setprio(0);
    BAR();
    // ---------------- phase B: mi 4..7 x ni 0..3 (bf reused) ----
    #pragma unroll
    for (int mi = 0; mi < 4; ++mi)
      af[mi] = *(const short8*)(bufA + (wm*128 + (mi+4)*16 + mrow) * 64 + cphys);
    if (tt + 3 < nt) {
      STAGE_B(tt + 3);
      asm volatile("s_waitcnt vmcnt(8)" ::: "memory");   // tile tt+1 landed
    } else if (tt + 3 == nt) {
      asm volatile("s_waitcnt vmcnt(4)" ::: "memory");   // tile nt-2 landed
    } else if (tt + 2 == nt) {
      asm volatile("s_waitcnt vmcnt(0)" ::: "memory");   // tile nt-1 landed
    }
    BAR();
    __builtin_amdgcn_s_setprio(1);
    #pragma unroll
    for (int mi = 0; mi < 4; ++mi)
      #pragma unroll
      for (int ni = 0; ni < 4; ++ni)
        acc[mi+4][ni] = __builtin_amdgcn_mfma_f32_16x16x32_bf16(af[mi], bf[ni], acc[mi+4][ni], 0, 0, 0);
    __builtin_amdgcn_s_setprio(0);
    BAR();
  }
  #undef STAGE_A
  #undef STAGE_B

  // epilogue: C/D layout col = lane&15, row = (lane>>4)*4 + reg
  const int crow = kq * 4;
  float bv[4];
  #pragma unroll
  for (int ni = 0; ni < 4; ++ni)
    bv[ni] = (EPI != 0) ? bias[col0 + wn*64 + ni*16 + mrow] : 0.0f;
  #pragma unroll
  for (int mi = 0; mi < 8; ++mi) {
    #pragma unroll
    for (int r = 0; r < 4; ++r) {
      const int row = row0 + wm*128 + mi*16 + crow + r;
      uint16_t* Cr = C + (size_t)row * N + col0 + wn*64 + mrow;
      #pragma unroll
      for (int ni = 0; ni < 4; ++ni) {
        float v = acc[mi][ni][r] + bv[ni];
        if (EPI == 2) v = gelu_f(v);
        Cr[ni*16] = f2bf(v);
      }
    }
  }
}

// ----- GEMM 64x64 tile, BK=64, full-K, fused bias + fp32 residual ----------
// grid (N/64, M/64) = 1024 blocks for N=1024 -> 4 blocks/CU. fp32 out.
__global__ __launch_bounds__(256) void gemm64(
    const uint16_t* __restrict__ A, const uint16_t* __restrict__ Bm,
    const float* __restrict__ bias, const float* __restrict__ res,
    float* __restrict__ out, int M, int N, int K)
{
  __shared__ __align__(16) uint16_t As[64*64];    // 8 KB
  __shared__ __align__(16) uint16_t Bs[64*64];    // 8 KB
  const int t = threadIdx.x;
  const int l = t & 63;
  const int w = t >> 6;
  const int row0 = blockIdx.y * 64;
  const int col0 = blockIdx.x * 64;
  const int wm = (w >> 1) * 32, wn = (w & 1) * 32;

  f32x4 acc[2][2];
  #pragma unroll
  for (int i = 0; i < 2; ++i)
    #pragma unroll
    for (int j = 0; j < 2; ++j)
      #pragma unroll
      for (int e = 0; e < 4; ++e) acc[i][j][e] = 0.0f;

  const int sr8 = t >> 3;
  const int sg  = (t & 7) ^ (sr8 & 7);
  const uint16_t* aG = A  + (size_t)(row0 + sr8) * K + sg * 8;
  const uint16_t* bG = Bm + (size_t)(col0 + sr8) * K + sg * 8;
  char* aL = (char*)As + t * 16;
  char* bL = (char*)Bs + t * 16;
  const int mrow = l & 15;
  const int kq = l >> 4;

  for (int k0 = 0; k0 < K; k0 += 64) {
    gl_lds16(aG + k0,                    aL);
    gl_lds16(aG + k0 + (size_t)32 * K,   aL + 4096);
    gl_lds16(bG + k0,                    bL);
    gl_lds16(bG + k0 + (size_t)32 * K,   bL + 4096);
    __syncthreads();
    #pragma unroll
    for (int ks = 0; ks < 2; ++ks) {
      const int pa = ((ks*4 + kq) ^ (mrow & 7)) * 16;
      short8 af[2], bfr[2];
      #pragma unroll
      for (int mi = 0; mi < 2; ++mi)
        af[mi] = *(const short8*)((const char*)As + (wm + mi*16 + mrow) * 128 + pa);
      #pragma unroll
      for (int ni = 0; ni < 2; ++ni)
        bfr[ni] = *(const short8*)((const char*)Bs + (wn + ni*16 + mrow) * 128 + pa);
      #pragma unroll
      for (int mi = 0; mi < 2; ++mi)
        #pragma unroll
        for (int ni = 0; ni < 2; ++ni)
          acc[mi][ni] = __builtin_amdgcn_mfma_f32_16x16x32_bf16(af[mi], bfr[ni], acc[mi][ni], 0, 0, 0);
    }
    __syncthreads();
  }

  const int crow = (l >> 4) * 4;
  float bv[2];
  #pragma unroll
  for (int ni = 0; ni < 2; ++ni)
    bv[ni] = bias[col0 + wn + ni*16 + mrow];
  #pragma unroll
  for (int mi = 0; mi < 2; ++mi)
    #pragma unroll
    for (int r = 0; r < 4; ++r) {
      const int row = row0 + wm + mi*16 + crow + r;
      #pragma unroll
      for (int ni = 0; ni < 2; ++ni) {
        const int col = col0 + wn + ni*16 + mrow;
        out[(size_t)row * N + col] = acc[mi][ni][r] + bv[ni] + res[(size_t)row * N + col];
      }
    }
}

// --------------------- local-window attention (MFMA) -----------------------
#define TQ    32
#define NKT   18
#define NKP   (NKT*16)   // 288 key slots
#define KSTR  72         // Qs/KV row stride (bf16)
#define PSTR  296        // Ps/Vt row stride (bf16)

__global__ __launch_bounds__(256) void attn_kernel(const uint16_t* __restrict__ qkv,
                                                   uint16_t* __restrict__ out)
{
  __shared__ uint16_t Qs[TQ * KSTR];
  __shared__ uint16_t Ps[TQ * PSTR];
  __shared__ uint16_t KV[NKP * KSTR];
  const int t = threadIdx.x, l = t & 63, w = t >> 6;
  const int b = blockIdx.z, hh = blockIdx.y, q0 = blockIdx.x * TQ;
  const int k0 = (q0 - WIN > 0) ? (q0 - WIN) : 0;
  const int kend_ = q0 + TQ + WIN;
  const int kend = (kend_ < SEQ) ? kend_ : SEQ;
  const int nk = kend - k0;

  {
    const int r = t >> 3, gg = t & 7;
    const uint4 qv = *(const uint4*)(qkv + (size_t)(b*SEQ + q0 + r) * 3072 + hh*64 + gg*8);
    *(uint4*)((char*)Qs + r*(KSTR*2) + gg*16) = qv;
    for (int j = r; j < NKP; j += 32) {
      uint4 kv; kv.x = 0; kv.y = 0; kv.z = 0; kv.w = 0;
      if (j < nk)
        kv = *(const uint4*)(qkv + (size_t)(b*SEQ + k0 + j) * 3072 + 1024 + hh*64 + gg*8);
      *(uint4*)((char*)KV + j*(KSTR*2) + gg*16) = kv;
    }
  }
  __syncthreads();

  if (w < 2) {
    const int rb = w * 16;
    const int mrow = l & 15, q4 = l >> 4;
    const short8 aq0 = *(const short8*)((const char*)Qs + (rb + mrow)*(KSTR*2) + q4*16);
    const short8 aq1 = *(const short8*)((const char*)Qs + (rb + mrow)*(KSTR*2) + 64 + q4*16);
    f32x4 cacc[NKT];
    #pragma unroll
    for (int ct = 0; ct < NKT; ++ct) {
      f32x4 c; c[0]=0.f; c[1]=0.f; c[2]=0.f; c[3]=0.f;
      const short8 b0 = *(const short8*)((const char*)KV + (ct*16 + mrow)*(KSTR*2) + q4*16);
      const short8 b1 = *(const short8*)((const char*)KV + (ct*16 + mrow)*(KSTR*2) + 64 + q4*16);
      c = __builtin_amdgcn_mfma_f32_16x16x32_bf16(aq0, b0, c, 0, 0, 0);
      c = __builtin_amdgcn_mfma_f32_16x16x32_bf16(aq1, b1, c, 0, 0, 0);
      cacc[ct] = c;
    }
    #pragma unroll
    for (int r = 0; r < 4; ++r) {
      const int iq = q0 + rb + q4*4 + r;
      float m = -1e30f;
      #pragma unroll
      for (int ct = 0; ct < NKT; ++ct) {
        const int jj = ct*16 + mrow;
        const int j = k0 + jj;
        const bool ok = (jj < nk) && (j >= iq - WIN) && (j <= iq + WIN);
        const float s = ok ? cacc[ct][r] * 0.125f : -1e30f;
        cacc[ct][r] = s;
        m = fmaxf(m, s);
      }
      m = fmaxf(m, __shfl_xor(m, 1, 64));
      m = fmaxf(m, __shfl_xor(m, 2, 64));
      m = fmaxf(m, __shfl_xor(m, 4, 64));
      m = fmaxf(m, __shfl_xor(m, 8, 64));
      float s = 0.f;
      #pragma unroll
      for (int ct = 0; ct < NKT; ++ct) {
        const float e = __expf(cacc[ct][r] - m);
        cacc[ct][r] = e;
        s += e;
      }
      s += __shfl_xor(s, 1, 64);
      s += __shfl_xor(s, 2, 64);
      s += __shfl_xor(s, 4, 64);
      s += __shfl_xor(s, 8, 64);
      const float rinv = 1.0f / s;
      #pragma unroll
      for (int ct = 0; ct < NKT; ++ct)
        Ps[(rb + q4*4 + r) * PSTR + ct*16 + mrow] = f2bf(cacc[ct][r] * rinv);
    }
  }
  __syncthreads();

  {
    uint16_t* Vt = KV;
    const int gg = t & 7;
    for (int j = t >> 3; j < NKP; j += 32) {
      if (j < nk) {
        const uint4 v = *(const uint4*)(qkv + (size_t)(b*SEQ + k0 + j) * 3072 + 2048 + hh*64 + gg*8);
        uint16_t e[8] = { (uint16_t)(v.x & 0xffff), (uint16_t)(v.x >> 16),
                          (uint16_t)(v.y & 0xffff), (uint16_t)(v.y >> 16),
                          (uint16_t)(v.z & 0xffff), (uint16_t)(v.z >> 16),
                          (uint16_t)(v.w & 0xffff), (uint16_t)(v.w >> 16) };
        #pragma unroll
        for (int dd = 0; dd < 8; ++dd) Vt[(gg*8 + dd) * PSTR + j] = e[dd];
      } else {
        #pragma unroll
        for (int dd = 0; dd < 8; ++dd) Vt[(gg*8 + dd) * PSTR + j] = 0;
      }
    }
  }
  __syncthreads();

  {
    const uint16_t* Vt = KV;
    const int mrow = l & 15, q4 = l >> 4;
    const int rt = w & 1, dt0 = (w >> 1) * 2;
    f32x4 o0, o1;
    #pragma unroll
    for (int e = 0; e < 4; ++e) { o0[e] = 0.f; o1[e] = 0.f; }
    #pragma unroll
    for (int ks = 0; ks < 9; ++ks) {
      const short8 a  = *(const short8*)((const char*)Ps + (rt*16 + mrow)*(PSTR*2) + ks*64 + q4*16);
      const short8 v0 = *(const short8*)((const char*)Vt + ((dt0  )*16 + mrow)*(PSTR*2) + ks*64 + q4*16);
      const short8 v1 = *(const short8*)((const char*)Vt + ((dt0+1)*16 + mrow)*(PSTR*2) + ks*64 + q4*16);
      o0 = __builtin_amdgcn_mfma_f32_16x16x32_bf16(a, v0, o0, 0, 0, 0);
      o1 = __builtin_amdgcn_mfma_f32_16x16x32_bf16(a, v1, o1, 0, 0, 0);
    }
    #pragma unroll
    for (int r = 0; r < 4; ++r) {
      const int iq = q0 + rt*16 + q4*4 + r;
      const size_t rowoff = (size_t)(b*SEQ + iq) * DMODEL + hh*64;
      out[rowoff + (dt0  )*16 + mrow] = f2bf(o0[r]);
      out[rowoff + (dt0+1)*16 + mrow] = f2bf(o1[r]);
    }
  }
}

// --------------------------------- launch ----------------------------------
extern "C" void kernel_launch(void* const* d_in, const int* in_sizes, int n_in,
                              void* d_out, int out_size, void* d_ws, size_t ws_size,
                              hipStream_t stream)
{
  const float* x    = (const float*)d_in[0];
  const float* ln1g = (const float*)d_in[1];
  const float* ln1b = (const float*)d_in[2];
  const float* wqkv = (const float*)d_in[3];
  const float* wout = (const float*)d_in[4];
  const float* bout = (const float*)d_in[5];
  const float* ln2g = (const float*)d_in[6];
  const float* ln2b = (const float*)d_in[7];
  const float* wff1 = (const float*)d_in[8];
  const float* bff1 = (const float*)d_in[9];
  const float* wff2 = (const float*)d_in[10];
  const float* bff2 = (const float*)d_in[11];
  float* out = (float*)d_out;

  char* ws = (char*)d_ws;
  const size_t MB = (size_t)1 << 20;
  uint16_t* Wqkv = (uint16_t*)(ws);            //  0-6
  uint16_t* Wout = (uint16_t*)(ws +  6*MB);    //  6-8
  uint16_t* Wff1 = (uint16_t*)(ws +  8*MB);    //  8-16
  uint16_t* Wff2 = (uint16_t*)(ws + 16*MB);    // 16-24
  uint16_t* QKV  = (uint16_t*)(ws + 24*MB);    // 24-48 (dead after attn)
  uint16_t* H1   = (uint16_t*)(ws + 48*MB);    // 48-56 h1 -> attn_out
  uint16_t* AT   = H1;
  float*    X2f  = (float*)   (ws + 56*MB);    // 56-72 fp32 (live to end)
  uint16_t* H2   = (uint16_t*)(ws + 72*MB);    // 72-80
  uint16_t* FF1  = (uint16_t*)(ws + 24*MB);    // 24-56 (qkv+attn dead)
  // high-water: 80 MB

  // 1) weights fp32->bf16 + h1 = LN1(x)   (fused, 16384 blocks)
  cvtln_kernel<<<16384, 256, 0, stream>>>(wqkv, wout, wff1, wff2,
                                          Wqkv, Wout, Wff1, Wff2,
                                          x, ln1g, ln1b, H1);
  // 2) qkv = h1 @ w_qkv^T                 (256² deep-pipelined, 192 blocks)
  gemm256<0><<<dim3(3072/256, MTOK/256), 512, 0, stream>>>(H1, Wqkv, nullptr, QKV, MTOK, 3072, DMODEL);
  // 3) attn_out = local_attention(qkv)
  attn_kernel<<<dim3(SEQ/TQ, NHEAD, NB), 256, 0, stream>>>(QKV, AT);
  // 4) x2 = attn_out @ w_out^T + b_out + x  (1024 blocks, 4/CU, fp32)
  gemm64<<<dim3(DMODEL/64, MTOK/64), 256, 0, stream>>>(AT, Wout, bout, x, X2f, MTOK, DMODEL, DMODEL);
  // 5) h2 = LN2(x2)
  ln_kernel<<<MTOK, 256, 0, stream>>>(X2f, ln2g, ln2b, H2);
  // 6) ff1 = gelu(h2 @ w_ff1^T + b_ff1)   (256² deep-pipelined, 256 blocks)
  gemm256<2><<<dim3(FFDIM/256, MTOK/256), 512, 0, stream>>>(H2, Wff1, bff1, FF1, MTOK, FFDIM, DMODEL);
  // 7) out = ff1 @ w_ff2^T + b_ff2 + x2   (1024 blocks, 4/CU, K=4096, fp32)
  gemm64<<<dim3(DMODEL/64, MTOK/64), 256, 0, stream>>>(FF1, Wff2, bff2, X2f, out, MTOK, DMODEL, FFDIM);
}

// Round 2
// 314.825 us; speedup vs baseline: 1.0880x; 1.0535x over previous
//
#include <hip/hip_runtime.h>
#include <stdint.h>

#define SEQ    2048
#define NB     2
#define DMODEL 1024
#define NHEAD  16
#define HDIM   64
#define FFDIM  4096
#define WIN    128
#define MTOK   (NB*SEQ)   // 4096 tokens

typedef short short8 __attribute__((ext_vector_type(8)));  // 8 bf16 (4 VGPRs)
typedef float f32x4  __attribute__((ext_vector_type(4)));

__device__ __forceinline__ float bf2f(uint16_t h){ return __uint_as_float(((uint32_t)h) << 16); }
__device__ __forceinline__ uint16_t f2bf(float f){           // RNE f32->bf16
  uint32_t u = __float_as_uint(f);
  u += 0x7fffu + ((u >> 16) & 1u);
  return (uint16_t)(u >> 16);
}

// tanh-form GELU, branch-free; max |delta| vs exact erf-GELU ~3e-3.
__device__ __forceinline__ float gelu_f(float v){
  float u = 0.7978845608028654f * v * (1.0f + 0.044715f * v * v);
  u = fminf(fmaxf(u, -10.0f), 10.0f);
  const float e = __expf(2.0f * u);
  const float th = (e - 1.0f) / (e + 1.0f);
  return 0.5f * v * (1.0f + th);
}

__device__ __forceinline__ void gl_lds16(const void* g, void* l) {
  __builtin_amdgcn_global_load_lds((const __attribute__((address_space(1))) void*)g,
                                   (__attribute__((address_space(3))) void*)l, 16, 0, 0);
}

// raw workgroup barrier WITHOUT the __syncthreads() vmcnt(0) drain.
__device__ __forceinline__ void BAR() {
  asm volatile("" ::: "memory");
  __builtin_amdgcn_s_barrier();
  asm volatile("" ::: "memory");
}

// ---- fused: weights fp32->bf16 (blocks 0..12287) + LN1 (blocks 12288..16383)
__global__ __launch_bounds__(256) void cvtln_kernel(
    const float* __restrict__ s0, const float* __restrict__ s1,
    const float* __restrict__ s2, const float* __restrict__ s3,
    uint16_t* __restrict__ d0, uint16_t* __restrict__ d1,
    uint16_t* __restrict__ d2, uint16_t* __restrict__ d3,
    const float* __restrict__ x, const float* __restrict__ g,
    const float* __restrict__ b, uint16_t* __restrict__ y)
{
  __shared__ float red[8];
  const int t = threadIdx.x;
  if (blockIdx.x < 12288) {
    size_t i = (size_t)blockIdx.x * 256 + t;   // float4 index; 3,145,728 total
    const float* s; uint16_t* d; size_t off;
    if      (i <  768*1024) { s = s0; d = d0; off = i; }
    else if (i < 1024*1024) { s = s1; d = d1; off = i -  768*1024; }
    else if (i < 2048*1024) { s = s2; d = d2; off = i - 1024*1024; }
    else                    { s = s3; d = d3; off = i - 2048*1024; }
    const float4 v = ((const float4*)s)[off];
    uint2 o;
    o.x = (uint32_t)f2bf(v.x) | ((uint32_t)f2bf(v.y) << 16);
    o.y = (uint32_t)f2bf(v.z) | ((uint32_t)f2bf(v.w) << 16);
    ((uint2*)d)[off] = o;
  } else {
    const int row = blockIdx.x - 12288;
    const float4 v = ((const float4*)(x + (size_t)row * DMODEL))[t];
    float s1 = v.x + v.y + v.z + v.w;
    float s2 = v.x*v.x + v.y*v.y + v.z*v.z + v.w*v.w;
    #pragma unroll
    for (int off = 32; off; off >>= 1) { s1 += __shfl_xor(s1, off, 64); s2 += __shfl_xor(s2, off, 64); }
    const int w = t >> 6;
    if ((t & 63) == 0) { red[w] = s1; red[4+w] = s2; }
    __syncthreads();
    s1 = red[0]+red[1]+red[2]+red[3];
    s2 = red[4]+red[5]+red[6]+red[7];
    const float mu = s1 * (1.0f/DMODEL);
    const float var = s2 * (1.0f/DMODEL) - mu*mu;
    const float rs = rsqrtf(var + 1e-5f);
    const float4 gv = ((const float4*)g)[t];
    const float4 bv = ((const float4*)b)[t];
    uint2 o;
    o.x = (uint32_t)f2bf((v.x-mu)*rs*gv.x + bv.x) | ((uint32_t)f2bf((v.y-mu)*rs*gv.y + bv.y) << 16);
    o.y = (uint32_t)f2bf((v.z-mu)*rs*gv.z + bv.z) | ((uint32_t)f2bf((v.w-mu)*rs*gv.w + bv.w) << 16);
    ((uint2*)(y + (size_t)row * DMODEL))[t] = o;
  }
}

// -------- LayerNorm: fp32 in -> bf16 out; one row (1024) per block ---------
__global__ __launch_bounds__(256) void ln_kernel(const float* __restrict__ x,
                                                 const float* __restrict__ g,
                                                 const float* __restrict__ b,
                                                 uint16_t* __restrict__ y)
{
  const int row = blockIdx.x;
  const int t = threadIdx.x;
  const float4 v = ((const float4*)(x + (size_t)row * DMODEL))[t];
  float s1 = v.x + v.y + v.z + v.w;
  float s2 = v.x*v.x + v.y*v.y + v.z*v.z + v.w*v.w;
  #pragma unroll
  for (int off = 32; off; off >>= 1) { s1 += __shfl_xor(s1, off, 64); s2 += __shfl_xor(s2, off, 64); }
  __shared__ float red[8];
  const int w = t >> 6;
  if ((t & 63) == 0) { red[w] = s1; red[4+w] = s2; }
  __syncthreads();
  s1 = red[0]+red[1]+red[2]+red[3];
  s2 = red[4]+red[5]+red[6]+red[7];
  const float mu = s1 * (1.0f/DMODEL);
  const float var = s2 * (1.0f/DMODEL) - mu*mu;
  const float rs = rsqrtf(var + 1e-5f);
  const float4 gv = ((const float4*)g)[t];
  const float4 bv = ((const float4*)b)[t];
  uint2 o;
  o.x = (uint32_t)f2bf((v.x-mu)*rs*gv.x + bv.x) | ((uint32_t)f2bf((v.y-mu)*rs*gv.y + bv.y) << 16);
  o.y = (uint32_t)f2bf((v.z-mu)*rs*gv.z + bv.z) | ((uint32_t)f2bf((v.w-mu)*rs*gv.w + bv.w) << 16);
  ((uint2*)(y + (size_t)row * DMODEL))[t] = o;
}

// ============ 256x256 deep-pipelined GEMM: C = A @ Bm^T (bf16 out) =========
// BK=32, 4-buffer LDS ring (128 KB), 512 thr / 8 waves, counted vmcnt(8),
// raw s_barrier, setprio around MFMA. EPI: 0 = none, 2 = bias + GELU.
template<int EPI>
__global__ __launch_bounds__(512, 2) void gemm256(
    const uint16_t* __restrict__ A, const uint16_t* __restrict__ Bm,
    const float* __restrict__ bias, uint16_t* __restrict__ C,
    int M, int N, int K)
{
  __shared__ __align__(16) uint16_t L[4 * 16384];   // 128 KB
  const int t = threadIdx.x;
  const int l = t & 63;
  const int w = t >> 6;
  const int wm = w >> 2, wn = w & 3;                // 2 x 4 wave grid
  const int row0 = blockIdx.y * 256, col0 = blockIdx.x * 256;
  const int mrow = l & 15, kq = l >> 4;
  const int nt = K >> 5;                            // K-tiles of 32

  f32x4 acc[8][4];
  #pragma unroll
  for (int i = 0; i < 8; ++i)
    #pragma unroll
    for (int j = 0; j < 4; ++j)
      #pragma unroll
      for (int e = 0; e < 4; ++e) acc[i][j][e] = 0.0f;

  const int sr = t >> 2;                            // row-in-half 0..127
  const int kl = (t & 3) ^ ((t >> 3) & 3);          // logical k-chunk 0..3
  const uint16_t* aG = A  + (size_t)(row0 + sr) * K + kl * 8;
  const uint16_t* bG = Bm + (size_t)(col0 + sr) * K + kl * 8;
  char* const lds = (char*)L;
  const int soff = t * 16;

  #define STAGE_A(tt_) { char* d_ = lds + ((tt_) & 3) * 32768 + soff; \
      gl_lds16(aG + (tt_) * 32, d_); \
      gl_lds16(aG + (size_t)128 * K + (tt_) * 32, d_ + 8192); }
  #define STAGE_B(tt_) { char* d_ = lds + ((tt_) & 3) * 32768 + 16384 + soff; \
      gl_lds16(bG + (tt_) * 32, d_); \
      gl_lds16(bG + (size_t)128 * K + (tt_) * 32, d_ + 8192); }

  STAGE_A(0); STAGE_B(0);
  STAGE_A(1); STAGE_B(1);
  STAGE_A(2); STAGE_B(2);
  asm volatile("s_waitcnt vmcnt(8)" ::: "memory");
  BAR();

  const int cphys = (kq ^ ((mrow >> 1) & 3)) << 4;  // physical chunk byte off

  for (int tt = 0; tt < nt; ++tt) {
    char* const bufA = lds + (tt & 3) * 32768;
    char* const bufB = bufA + 16384;
    // ---------------- phase A: mi 0..3 x ni 0..3 ----------------
    short8 bf[4], af[4];
    #pragma unroll
    for (int ni = 0; ni < 4; ++ni)
      bf[ni] = *(const short8*)(bufB + (wn*64 + ni*16 + mrow) * 64 + cphys);
    #pragma unroll
    for (int mi = 0; mi < 4; ++mi)
      af[mi] = *(const short8*)(bufA + (wm*128 + mi*16 + mrow) * 64 + cphys);
    if (tt + 3 < nt) STAGE_A(tt + 3);
    BAR();
    __builtin_amdgcn_s_setprio(1);
    #pragma unroll
    for (int mi = 0; mi < 4; ++mi)
      #pragma unroll
      for (int ni = 0; ni < 4; ++ni)
        acc[mi][ni] = __builtin_amdgcn_mfma_f32_16x16x32_bf16(af[mi], bf[ni], acc[mi][ni], 0, 0, 0);
    __builtin_amdgcn_s_setprio(0);
    BAR();
    // ---------------- phase B: mi 4..7 x ni 0..3 (bf reused) ----
    #pragma unroll
    for (int mi = 0; mi < 4; ++mi)
      af[mi] = *(const short8*)(bufA + (wm*128 + (mi+4)*16 + mrow) * 64 + cphys);
    if (tt + 3 < nt) {
      STAGE_B(tt + 3);
      asm volatile("s_waitcnt vmcnt(8)" ::: "memory");   // tile tt+1 landed
    } else if (tt + 3 == nt) {
      asm volatile("s_waitcnt vmcnt(4)" ::: "memory");
    } else if (tt + 2 == nt) {
      asm volatile("s_waitcnt vmcnt(0)" ::: "memory");
    }
    BAR();
    __builtin_amdgcn_s_setprio(1);
    #pragma unroll
    for (int mi = 0; mi < 4; ++mi)
      #pragma unroll
      for (int ni = 0; ni < 4; ++ni)
        acc[mi+4][ni] = __builtin_amdgcn_mfma_f32_16x16x32_bf16(af[mi], bf[ni], acc[mi+4][ni], 0, 0, 0);
    __builtin_amdgcn_s_setprio(0);
    BAR();
  }
  #undef STAGE_A
  #undef STAGE_B

  const int crow = kq * 4;
  float bv[4];
  #pragma unroll
  for (int ni = 0; ni < 4; ++ni)
    bv[ni] = (EPI != 0) ? bias[col0 + wn*64 + ni*16 + mrow] : 0.0f;
  #pragma unroll
  for (int mi = 0; mi < 8; ++mi) {
    #pragma unroll
    for (int r = 0; r < 4; ++r) {
      const int row = row0 + wm*128 + mi*16 + crow + r;
      uint16_t* Cr = C + (size_t)row * N + col0 + wn*64 + mrow;
      #pragma unroll
      for (int ni = 0; ni < 4; ++ni) {
        float v = acc[mi][ni][r] + bv[ni];
        if (EPI == 2) v = gelu_f(v);
        Cr[ni*16] = f2bf(v);
      }
    }
  }
}

// ===== 128x128 deep-pipelined GEMM: out = A @ Bm^T + bias + res (fp32) =====
// BK=64, 4-buffer LDS ring (128 KB), 512 thr / 8 waves (2M x 4N), per-wave
// 64x32 output (acc[4][2]). Per K-tile: 2 phases (k-slice split), 4
// global_load_lds, counted vmcnt(8) once per tile, raw s_barrier, setprio.
// LDS: row = 64 bf16 = 128 B = 8 chunks; LDS[r][p] = G[r][p ^ (r&7)]
// (stage fetches global chunk (t&7)^((t>>3)&7)); readers use
// phys = (ks*4+kq) ^ (mrow&7) -> conflict-free (proven pattern).
// grid: (M/128, N/128), blockIdx.x = row-block so same-A-panel blocks land
// on one XCD (A fetched once), same-B-panel blocks spread across XCDs.
__global__ __launch_bounds__(512, 2) void gemm128r(
    const uint16_t* __restrict__ A, const uint16_t* __restrict__ Bm,
    const float* __restrict__ bias, const float* __restrict__ res,
    float* __restrict__ out, int M, int N, int K)
{
  __shared__ __align__(16) uint16_t L[4 * 16384];   // 128 KB (4 x (16KB A + 16KB B))
  const int t = threadIdx.x;
  const int l = t & 63;
  const int w = t >> 6;
  const int wm = w >> 2, wn = w & 3;                // 2 x 4 wave grid
  const int row0 = blockIdx.x * 128, col0 = blockIdx.y * 128;
  const int mrow = l & 15, kq = l >> 4;
  const int nt = K >> 6;                            // K-tiles of 64

  f32x4 acc[4][2];
  #pragma unroll
  for (int i = 0; i < 4; ++i)
    #pragma unroll
    for (int j = 0; j < 2; ++j)
      #pragma unroll
      for (int e = 0; e < 4; ++e) acc[i][j][e] = 0.0f;

  const int sr = t >> 3;                            // row-in-half 0..63
  const int kl = (t & 7) ^ (sr & 7);                // swizzled global chunk
  const uint16_t* aG = A  + (size_t)(row0 + sr) * K + kl * 8;
  const uint16_t* bG = Bm + (size_t)(col0 + sr) * K + kl * 8;
  char* const lds = (char*)L;
  const int soff = t * 16;

  #define STAGE_A(tt_) { char* d_ = lds + ((tt_) & 3) * 32768 + soff; \
      gl_lds16(aG + (tt_) * 64, d_); \
      gl_lds16(aG + (size_t)64 * K + (tt_) * 64, d_ + 8192); }
  #define STAGE_B(tt_) { char* d_ = lds + ((tt_) & 3) * 32768 + 16384 + soff; \
      gl_lds16(bG + (tt_) * 64, d_); \
      gl_lds16(bG + (size_t)64 * K + (tt_) * 64, d_ + 8192); }

  STAGE_A(0); STAGE_B(0);
  STAGE_A(1); STAGE_B(1);
  STAGE_A(2); STAGE_B(2);
  asm volatile("s_waitcnt vmcnt(8)" ::: "memory");
  BAR();

  for (int tt = 0; tt < nt; ++tt) {
    char* const bufA = lds + (tt & 3) * 32768;
    char* const bufB = bufA + 16384;
    // ---------------- phase A: k-slice 0 ----------------
    {
      const int pa = (kq ^ (mrow & 7)) * 16;        // ks=0
      short8 af[4], bf[2];
      #pragma unroll
      for (int ni = 0; ni < 2; ++ni)
        bf[ni] = *(const short8*)(bufB + (wn*32 + ni*16 + mrow) * 128 + pa);
      #pragma unroll
      for (int mi = 0; mi < 4; ++mi)
        af[mi] = *(const short8*)(bufA + (wm*64 + mi*16 + mrow) * 128 + pa);
      if (tt + 3 < nt) STAGE_A(tt + 3);
      BAR();
      __builtin_amdgcn_s_setprio(1);
      #pragma unroll
      for (int mi = 0; mi < 4; ++mi)
        #pragma unroll
        for (int ni = 0; ni < 2; ++ni)
          acc[mi][ni] = __builtin_amdgcn_mfma_f32_16x16x32_bf16(af[mi], bf[ni], acc[mi][ni], 0, 0, 0);
      __builtin_amdgcn_s_setprio(0);
      BAR();
    }
    // ---------------- phase B: k-slice 1 ----------------
    {
      const int pa = ((4 + kq) ^ (mrow & 7)) * 16;  // ks=1
      short8 af[4], bf[2];
      #pragma unroll
      for (int ni = 0; ni < 2; ++ni)
        bf[ni] = *(const short8*)(bufB + (wn*32 + ni*16 + mrow) * 128 + pa);
      #pragma unroll
      for (int mi = 0; mi < 4; ++mi)
        af[mi] = *(const short8*)(bufA + (wm*64 + mi*16 + mrow) * 128 + pa);
      if (tt + 3 < nt) {
        STAGE_B(tt + 3);
        asm volatile("s_waitcnt vmcnt(8)" ::: "memory");   // tile tt+1 landed
      } else if (tt + 3 == nt) {
        asm volatile("s_waitcnt vmcnt(4)" ::: "memory");
      } else if (tt + 2 == nt) {
        asm volatile("s_waitcnt vmcnt(0)" ::: "memory");
      }
      BAR();
      __builtin_amdgcn_s_setprio(1);
      #pragma unroll
      for (int mi = 0; mi < 4; ++mi)
        #pragma unroll
        for (int ni = 0; ni < 2; ++ni)
          acc[mi][ni] = __builtin_amdgcn_mfma_f32_16x16x32_bf16(af[mi], bf[ni], acc[mi][ni], 0, 0, 0);
      __builtin_amdgcn_s_setprio(0);
      BAR();
    }
  }
  #undef STAGE_A
  #undef STAGE_B

  const int crow = kq * 4;
  float bv[2];
  #pragma unroll
  for (int ni = 0; ni < 2; ++ni)
    bv[ni] = bias[col0 + wn*32 + ni*16 + mrow];
  #pragma unroll
  for (int mi = 0; mi < 4; ++mi)
    #pragma unroll
    for (int r = 0; r < 4; ++r) {
      const int row = row0 + wm*64 + mi*16 + crow + r;
      const size_t base = (size_t)row * N + col0 + wn*32 + mrow;
      #pragma unroll
      for (int ni = 0; ni < 2; ++ni)
        out[base + ni*16] = acc[mi][ni][r] + bv[ni] + res[base + ni*16];
    }
}

// --------------------- local-window attention (MFMA) -----------------------
#define TQ    32
#define NKT   18
#define NKP   (NKT*16)   // 288 key slots
#define KSTR  72         // Qs/KV row stride (bf16)
#define PSTR  296        // Ps row stride (bf16)
#define VSTR  320        // Vt row stride (bf16) = 40 chunks (multiple of 8)

// Vt chunk swizzle: phys = c ^ (d>>3) ^ ((d&3)<<1). Write side (d = gg*8+dd):
// spreads over gg -> 32 banks, 2-way b16 = free. Read side (d = dt*16+mrow):
// bits of mrow cover all 8 chunk groups -> even b128 spread.
__device__ __forceinline__ int vt_swz(int d){ return (d >> 3) ^ ((d & 3) << 1); }

__global__ __launch_bounds__(256) void attn_kernel(const uint16_t* __restrict__ qkv,
                                                   uint16_t* __restrict__ out)
{
  __shared__ uint16_t Qs[TQ * KSTR];     //  4.6 KB
  __shared__ uint16_t Ps[TQ * PSTR];     // 18.9 KB
  __shared__ uint16_t KV[NKP * KSTR];    // 41.5 KB; reused as Vt[64][VSTR] (40 KB)
  const int t = threadIdx.x, l = t & 63, w = t >> 6;
  const int b = blockIdx.z, hh = blockIdx.y, q0 = blockIdx.x * TQ;
  const int k0 = (q0 - WIN > 0) ? (q0 - WIN) : 0;
  const int kend_ = q0 + TQ + WIN;
  const int kend = (kend_ < SEQ) ? kend_ : SEQ;
  const int nk = kend - k0;

  // ---- stage Q + K (all threads) ----
  {
    const int r = t >> 3, gg = t & 7;
    const uint4 qv = *(const uint4*)(qkv + (size_t)(b*SEQ + q0 + r) * 3072 + hh*64 + gg*8);
    *(uint4*)((char*)Qs + r*(KSTR*2) + gg*16) = qv;
    for (int j = r; j < NKP; j += 32) {
      uint4 kv; kv.x = 0; kv.y = 0; kv.z = 0; kv.w = 0;
      if (j < nk)
        kv = *(const uint4*)(qkv + (size_t)(b*SEQ + k0 + j) * 3072 + 1024 + hh*64 + gg*8);
      *(uint4*)((char*)KV + j*(KSTR*2) + gg*16) = kv;
    }
  }

  // ---- waves 2,3: preload first half of V into regs (latency hidden) ----
  const int tt2 = t & 127;               // lane within the 2-wave group
  const int jl = tt2 >> 3, gg2 = tt2 & 7;
  uint4 va[9];
  if (w >= 2) {
    #pragma unroll
    for (int i = 0; i < 9; ++i) {
      uint4 z; z.x = 0; z.y = 0; z.z = 0; z.w = 0;
      const int j = jl + 16*i;
      va[i] = (j < nk)
        ? *(const uint4*)(qkv + (size_t)(b*SEQ + k0 + j) * 3072 + 2048 + hh*64 + gg2*8)
        : z;
    }
  }
  __syncthreads();

  // ---- waves 0,1: QK^T (reads Qs, KV) ----
  const int mrow = l & 15, q4 = l >> 4;
  f32x4 cacc[NKT];
  if (w < 2) {
    const int rb = w * 16;
    const short8 aq0 = *(const short8*)((const char*)Qs + (rb + mrow)*(KSTR*2) + q4*16);
    const short8 aq1 = *(const short8*)((const char*)Qs + (rb + mrow)*(KSTR*2) + 64 + q4*16);
    #pragma unroll
    for (int ct = 0; ct < NKT; ++ct) {
      f32x4 c; c[0]=0.f; c[1]=0.f; c[2]=0.f; c[3]=0.f;
      const short8 b0 = *(const short8*)((const char*)KV + (ct*16 + mrow)*(KSTR*2) + q4*16);
      const short8 b1 = *(const short8*)((const char*)KV + (ct*16 + mrow)*(KSTR*2) + 64 + q4*16);
      c = __builtin_amdgcn_mfma_f32_16x16x32_bf16(aq0, b0, c, 0, 0, 0);
      c = __builtin_amdgcn_mfma_f32_16x16x32_bf16(aq1, b1, c, 0, 0, 0);
      cacc[ct] = c;
    }
  }
  __syncthreads();   // waves 0,1 done reading KV -> waves 2,3 may overwrite

  if (w < 2) {
    // ---- softmax + Ps write ----
    const int rb = w * 16;
    #pragma unroll
    for (int r = 0; r < 4; ++r) {
      const int iq = q0 + rb + q4*4 + r;
      float m = -1e30f;
      #pragma unroll
      for (int ct = 0; ct < NKT; ++ct) {
        const int jj = ct*16 + mrow;
        const int j = k0 + jj;
        const bool ok = (jj < nk) && (j >= iq - WIN) && (j <= iq + WIN);
        const float s = ok ? cacc[ct][r] * 0.125f : -1e30f;
        cacc[ct][r] = s;
        m = fmaxf(m, s);
      }
      m = fmaxf(m, __shfl_xor(m, 1, 64));
      m = fmaxf(m, __shfl_xor(m, 2, 64));
      m = fmaxf(m, __shfl_xor(m, 4, 64));
      m = fmaxf(m, __shfl_xor(m, 8, 64));
      float s = 0.f;
      #pragma unroll
      for (int ct = 0; ct < NKT; ++ct) {
        const float e = __expf(cacc[ct][r] - m);
        cacc[ct][r] = e;
        s += e;
      }
      s += __shfl_xor(s, 1, 64);
      s += __shfl_xor(s, 2, 64);
      s += __shfl_xor(s, 4, 64);
      s += __shfl_xor(s, 8, 64);
      const float rinv = 1.0f / s;
      #pragma unroll
      for (int ct = 0; ct < NKT; ++ct)
        Ps[(rb + q4*4 + r) * PSTR + ct*16 + mrow] = f2bf(cacc[ct][r] * rinv);
    }
  } else {
    // ---- waves 2,3: transpose V into Vt (overlapped with softmax) ----
    uint16_t* Vt = KV;
    uint4 vb[9];
    #pragma unroll
    for (int i = 0; i < 9; ++i) {       // issue 2nd-half loads first
      uint4 z; z.x = 0; z.y = 0; z.z = 0; z.w = 0;
      const int j = jl + 16*(i+9);
      vb[i] = (j < nk)
        ? *(const uint4*)(qkv + (size_t)(b*SEQ + k0 + j) * 3072 + 2048 + hh*64 + gg2*8)
        : z;
    }
    #pragma unroll
    for (int i = 0; i < 18; ++i) {
      const uint4 v = (i < 9) ? va[i] : vb[i-9];
      const int j = jl + 16*i;
      const uint16_t e[8] = { (uint16_t)(v.x & 0xffff), (uint16_t)(v.x >> 16),
                              (uint16_t)(v.y & 0xffff), (uint16_t)(v.y >> 16),
                              (uint16_t)(v.z & 0xffff), (uint16_t)(v.z >> 16),
                              (uint16_t)(v.w & 0xffff), (uint16_t)(v.w >> 16) };
      #pragma unroll
      for (int dd = 0; dd < 8; ++dd) {
        const int dr = gg2*8 + dd;
        const int coff = (((j >> 3) ^ vt_swz(dr)) << 4) + ((j & 7) << 1);
        *(uint16_t*)((char*)Vt + dr*(VSTR*2) + coff) = e[dd];
      }
    }
  }
  __syncthreads();

  // ---- PV: all 4 waves ----
  {
    const uint16_t* Vt = KV;
    const int rt = w & 1, dt0 = (w >> 1) * 2;
    f32x4 o0, o1;
    #pragma unroll
    for (int e = 0; e < 4; ++e) { o0[e] = 0.f; o1[e] = 0.f; }
    const int d0 = (dt0  )*16 + mrow;
    const int d1 = (dt0+1)*16 + mrow;
    const int sw0 = vt_swz(d0), sw1 = vt_swz(d1);
    #pragma unroll
    for (int ks = 0; ks < 9; ++ks) {
      const short8 a  = *(const short8*)((const char*)Ps + (rt*16 + mrow)*(PSTR*2) + ks*64 + q4*16);
      const short8 v0 = *(const short8*)((const char*)Vt + d0*(VSTR*2) + (((ks*4 + q4) ^ sw0) << 4));
      const short8 v1 = *(const short8*)((const char*)Vt + d1*(VSTR*2) + (((ks*4 + q4) ^ sw1) << 4));
      o0 = __builtin_amdgcn_mfma_f32_16x16x32_bf16(a, v0, o0, 0, 0, 0);
      o1 = __builtin_amdgcn_mfma_f32_16x16x32_bf16(a, v1, o1, 0, 0, 0);
    }
    #pragma unroll
    for (int r = 0; r < 4; ++r) {
      const int iq = q0 + rt*16 + q4*4 + r;
      const size_t rowoff = (size_t)(b*SEQ + iq) * DMODEL + hh*64;
      out[rowoff + (dt0  )*16 + mrow] = f2bf(o0[r]);
      out[rowoff + (dt0+1)*16 + mrow] = f2bf(o1[r]);
    }
  }
}

// --------------------------------- launch ----------------------------------
extern "C" void kernel_launch(void* const* d_in, const int* in_sizes, int n_in,
                              void* d_out, int out_size, void* d_ws, size_t ws_size,
                              hipStream_t stream)
{
  const float* x    = (const float*)d_in[0];
  const float* ln1g = (const float*)d_in[1];
  const float* ln1b = (const float*)d_in[2];
  const float* wqkv = (const float*)d_in[3];
  const float* wout = (const float*)d_in[4];
  const float* bout = (const float*)d_in[5];
  const float* ln2g = (const float*)d_in[6];
  const float* ln2b = (const float*)d_in[7];
  const float* wff1 = (const float*)d_in[8];
  const float* bff1 = (const float*)d_in[9];
  const float* wff2 = (const float*)d_in[10];
  const float* bff2 = (const float*)d_in[11];
  float* out = (float*)d_out;

  char* ws = (char*)d_ws;
  const size_t MB = (size_t)1 << 20;
  uint16_t* Wqkv = (uint16_t*)(ws);            //  0-6
  uint16_t* Wout = (uint16_t*)(ws +  6*MB);    //  6-8
  uint16_t* Wff1 = (uint16_t*)(ws +  8*MB);    //  8-16
  uint16_t* Wff2 = (uint16_t*)(ws + 16*MB);    // 16-24
  uint16_t* QKV  = (uint16_t*)(ws + 24*MB);    // 24-48 (dead after attn)
  uint16_t* H1   = (uint16_t*)(ws + 48*MB);    // 48-56 h1 -> attn_out
  uint16_t* AT   = H1;
  float*    X2f  = (float*)   (ws + 56*MB);    // 56-72 fp32 (live to end)
  uint16_t* H2   = (uint16_t*)(ws + 72*MB);    // 72-80
  uint16_t* FF1  = (uint16_t*)(ws + 24*MB);    // 24-56 (qkv+attn dead)
  // high-water: 80 MB

  // 1) weights fp32->bf16 + h1 = LN1(x)   (fused, 16384 blocks)
  cvtln_kernel<<<16384, 256, 0, stream>>>(wqkv, wout, wff1, wff2,
                                          Wqkv, Wout, Wff1, Wff2,
                                          x, ln1g, ln1b, H1);
  // 2) qkv = h1 @ w_qkv^T                 (256² deep-pipelined, 192 blocks)
  gemm256<0><<<dim3(3072/256, MTOK/256), 512, 0, stream>>>(H1, Wqkv, nullptr, QKV, MTOK, 3072, DMODEL);
  // 3) attn_out = local_attention(qkv)
  attn_kernel<<<dim3(SEQ/TQ, NHEAD, NB), 256, 0, stream>>>(QKV, AT);
  // 4) x2 = attn_out @ w_out^T + b_out + x  (128² deep-pipelined, 256 blocks)
  gemm128r<<<dim3(MTOK/128, DMODEL/128), 512, 0, stream>>>(AT, Wout, bout, x, X2f, MTOK, DMODEL, DMODEL);
  // 5) h2 = LN2(x2)
  ln_kernel<<<MTOK, 256, 0, stream>>>(X2f, ln2g, ln2b, H2);
  // 6) ff1 = gelu(h2 @ w_ff1^T + b_ff1)   (256² deep-pipelined, 256 blocks)
  gemm256<2><<<dim3(FFDIM/256, MTOK/256), 512, 0, stream>>>(H2, Wff1, bff1, FF1, MTOK, FFDIM, DMODEL);
  // 7) out = ff1 @ w_ff2^T + b_ff2 + x2   (128² deep-pipelined, 256 blocks)
  gemm128r<<<dim3(MTOK/128, DMODEL/128), 512, 0, stream>>>(FF1, Wff2, bff2, X2f, out, MTOK, DMODEL, FFDIM);
}

// Round 3
// 308.928 us; speedup vs baseline: 1.1088x; 1.0191x over previous
//
#include <hip/hip_runtime.h>
#include <stdint.h>

#define SEQ    2048
#define NB     2
#define DMODEL 1024
#define NHEAD  16
#define HDIM   64
#define FFDIM  4096
#define WIN    128
#define MTOK   (NB*SEQ)   // 4096 tokens

typedef short short8 __attribute__((ext_vector_type(8)));  // 8 bf16 (4 VGPRs)
typedef float f32x4  __attribute__((ext_vector_type(4)));

__device__ __forceinline__ float bf2f(uint16_t h){ return __uint_as_float(((uint32_t)h) << 16); }
__device__ __forceinline__ uint16_t f2bf(float f){           // RNE f32->bf16
  uint32_t u = __float_as_uint(f);
  u += 0x7fffu + ((u >> 16) & 1u);
  return (uint16_t)(u >> 16);
}

// tanh-form GELU, branch-free; max |delta| vs exact erf-GELU ~3e-3.
__device__ __forceinline__ float gelu_f(float v){
  float u = 0.7978845608028654f * v * (1.0f + 0.044715f * v * v);
  u = fminf(fmaxf(u, -10.0f), 10.0f);
  const float e = __expf(2.0f * u);
  const float th = (e - 1.0f) / (e + 1.0f);
  return 0.5f * v * (1.0f + th);
}

__device__ __forceinline__ void gl_lds16(const void* g, void* l) {
  __builtin_amdgcn_global_load_lds((const __attribute__((address_space(1))) void*)g,
                                   (__attribute__((address_space(3))) void*)l, 16, 0, 0);
}

// raw workgroup barrier WITHOUT the __syncthreads() vmcnt(0) drain.
__device__ __forceinline__ void BAR() {
  asm volatile("" ::: "memory");
  __builtin_amdgcn_s_barrier();
  asm volatile("" ::: "memory");
}

// ---- fused: weights fp32->bf16 (blocks 0..12287) + LN1 (blocks 12288..16383)
__global__ __launch_bounds__(256) void cvtln_kernel(
    const float* __restrict__ s0, const float* __restrict__ s1,
    const float* __restrict__ s2, const float* __restrict__ s3,
    uint16_t* __restrict__ d0, uint16_t* __restrict__ d1,
    uint16_t* __restrict__ d2, uint16_t* __restrict__ d3,
    const float* __restrict__ x, const float* __restrict__ g,
    const float* __restrict__ b, uint16_t* __restrict__ y)
{
  __shared__ float red[8];
  const int t = threadIdx.x;
  if (blockIdx.x < 12288) {
    size_t i = (size_t)blockIdx.x * 256 + t;   // float4 index; 3,145,728 total
    const float* s; uint16_t* d; size_t off;
    if      (i <  768*1024) { s = s0; d = d0; off = i; }
    else if (i < 1024*1024) { s = s1; d = d1; off = i -  768*1024; }
    else if (i < 2048*1024) { s = s2; d = d2; off = i - 1024*1024; }
    else                    { s = s3; d = d3; off = i - 2048*1024; }
    const float4 v = ((const float4*)s)[off];
    uint2 o;
    o.x = (uint32_t)f2bf(v.x) | ((uint32_t)f2bf(v.y) << 16);
    o.y = (uint32_t)f2bf(v.z) | ((uint32_t)f2bf(v.w) << 16);
    ((uint2*)d)[off] = o;
  } else {
    const int row = blockIdx.x - 12288;
    const float4 v = ((const float4*)(x + (size_t)row * DMODEL))[t];
    float s1 = v.x + v.y + v.z + v.w;
    float s2 = v.x*v.x + v.y*v.y + v.z*v.z + v.w*v.w;
    #pragma unroll
    for (int off = 32; off; off >>= 1) { s1 += __shfl_xor(s1, off, 64); s2 += __shfl_xor(s2, off, 64); }
    const int w = t >> 6;
    if ((t & 63) == 0) { red[w] = s1; red[4+w] = s2; }
    __syncthreads();
    s1 = red[0]+red[1]+red[2]+red[3];
    s2 = red[4]+red[5]+red[6]+red[7];
    const float mu = s1 * (1.0f/DMODEL);
    const float var = s2 * (1.0f/DMODEL) - mu*mu;
    const float rs = rsqrtf(var + 1e-5f);
    const float4 gv = ((const float4*)g)[t];
    const float4 bv = ((const float4*)b)[t];
    uint2 o;
    o.x = (uint32_t)f2bf((v.x-mu)*rs*gv.x + bv.x) | ((uint32_t)f2bf((v.y-mu)*rs*gv.y + bv.y) << 16);
    o.y = (uint32_t)f2bf((v.z-mu)*rs*gv.z + bv.z) | ((uint32_t)f2bf((v.w-mu)*rs*gv.w + bv.w) << 16);
    ((uint2*)(y + (size_t)row * DMODEL))[t] = o;
  }
}

// -------- LayerNorm: fp32 in -> bf16 out; one row (1024) per block ---------
__global__ __launch_bounds__(256) void ln_kernel(const float* __restrict__ x,
                                                 const float* __restrict__ g,
                                                 const float* __restrict__ b,
                                                 uint16_t* __restrict__ y)
{
  const int row = blockIdx.x;
  const int t = threadIdx.x;
  const float4 v = ((const float4*)(x + (size_t)row * DMODEL))[t];
  float s1 = v.x + v.y + v.z + v.w;
  float s2 = v.x*v.x + v.y*v.y + v.z*v.z + v.w*v.w;
  #pragma unroll
  for (int off = 32; off; off >>= 1) { s1 += __shfl_xor(s1, off, 64); s2 += __shfl_xor(s2, off, 64); }
  __shared__ float red[8];
  const int w = t >> 6;
  if ((t & 63) == 0) { red[w] = s1; red[4+w] = s2; }
  __syncthreads();
  s1 = red[0]+red[1]+red[2]+red[3];
  s2 = red[4]+red[5]+red[6]+red[7];
  const float mu = s1 * (1.0f/DMODEL);
  const float var = s2 * (1.0f/DMODEL) - mu*mu;
  const float rs = rsqrtf(var + 1e-5f);
  const float4 gv = ((const float4*)g)[t];
  const float4 bv = ((const float4*)b)[t];
  uint2 o;
  o.x = (uint32_t)f2bf((v.x-mu)*rs*gv.x + bv.x) | ((uint32_t)f2bf((v.y-mu)*rs*gv.y + bv.y) << 16);
  o.y = (uint32_t)f2bf((v.z-mu)*rs*gv.z + bv.z) | ((uint32_t)f2bf((v.w-mu)*rs*gv.w + bv.w) << 16);
  ((uint2*)(y + (size_t)row * DMODEL))[t] = o;
}

// ============ 256x256 deep-pipelined GEMM: C = A @ Bm^T (bf16 out) =========
// BK=32, 4-buffer LDS ring (128 KB), 512 thr / 8 waves, counted vmcnt(8),
// raw s_barrier, setprio around MFMA.
// EPI: 0 = none; 1 = QKV (V-col blocks scatter to vt[b][h][d][2048]);
// EPI: 2 = bias + GELU.
template<int EPI>
__global__ __launch_bounds__(512, 2) void gemm256(
    const uint16_t* __restrict__ A, const uint16_t* __restrict__ Bm,
    const float* __restrict__ bias, uint16_t* __restrict__ C,
    uint16_t* __restrict__ vt, int M, int N, int K)
{
  __shared__ __align__(16) uint16_t L[4 * 16384];   // 128 KB
  const int t = threadIdx.x;
  const int l = t & 63;
  const int w = t >> 6;
  const int wm = w >> 2, wn = w & 3;                // 2 x 4 wave grid
  const int row0 = blockIdx.y * 256, col0 = blockIdx.x * 256;
  const int mrow = l & 15, kq = l >> 4;
  const int nt = K >> 5;                            // K-tiles of 32

  f32x4 acc[8][4];
  #pragma unroll
  for (int i = 0; i < 8; ++i)
    #pragma unroll
    for (int j = 0; j < 4; ++j)
      #pragma unroll
      for (int e = 0; e < 4; ++e) acc[i][j][e] = 0.0f;

  const int sr = t >> 2;                            // row-in-half 0..127
  const int kl = (t & 3) ^ ((t >> 3) & 3);          // logical k-chunk 0..3
  const uint16_t* aG = A  + (size_t)(row0 + sr) * K + kl * 8;
  const uint16_t* bG = Bm + (size_t)(col0 + sr) * K + kl * 8;
  char* const lds = (char*)L;
  const int soff = t * 16;

  #define STAGE_A(tt_) { char* d_ = lds + ((tt_) & 3) * 32768 + soff; \
      gl_lds16(aG + (tt_) * 32, d_); \
      gl_lds16(aG + (size_t)128 * K + (tt_) * 32, d_ + 8192); }
  #define STAGE_B(tt_) { char* d_ = lds + ((tt_) & 3) * 32768 + 16384 + soff; \
      gl_lds16(bG + (tt_) * 32, d_); \
      gl_lds16(bG + (size_t)128 * K + (tt_) * 32, d_ + 8192); }

  STAGE_A(0); STAGE_B(0);
  STAGE_A(1); STAGE_B(1);
  STAGE_A(2); STAGE_B(2);
  asm volatile("s_waitcnt vmcnt(8)" ::: "memory");
  BAR();

  const int cphys = (kq ^ ((mrow >> 1) & 3)) << 4;  // physical chunk byte off

  for (int tt = 0; tt < nt; ++tt) {
    char* const bufA = lds + (tt & 3) * 32768;
    char* const bufB = bufA + 16384;
    // ---------------- phase A: mi 0..3 x ni 0..3 ----------------
    short8 bf[4], af[4];
    #pragma unroll
    for (int ni = 0; ni < 4; ++ni)
      bf[ni] = *(const short8*)(bufB + (wn*64 + ni*16 + mrow) * 64 + cphys);
    #pragma unroll
    for (int mi = 0; mi < 4; ++mi)
      af[mi] = *(const short8*)(bufA + (wm*128 + mi*16 + mrow) * 64 + cphys);
    if (tt + 3 < nt) STAGE_A(tt + 3);
    BAR();
    __builtin_amdgcn_s_setprio(1);
    #pragma unroll
    for (int mi = 0; mi < 4; ++mi)
      #pragma unroll
      for (int ni = 0; ni < 4; ++ni)
        acc[mi][ni] = __builtin_amdgcn_mfma_f32_16x16x32_bf16(af[mi], bf[ni], acc[mi][ni], 0, 0, 0);
    __builtin_amdgcn_s_setprio(0);
    BAR();
    // ---------------- phase B: mi 4..7 x ni 0..3 (bf reused) ----
    #pragma unroll
    for (int mi = 0; mi < 4; ++mi)
      af[mi] = *(const short8*)(bufA + (wm*128 + (mi+4)*16 + mrow) * 64 + cphys);
    if (tt + 3 < nt) {
      STAGE_B(tt + 3);
      asm volatile("s_waitcnt vmcnt(8)" ::: "memory");   // tile tt+1 landed
    } else if (tt + 3 == nt) {
      asm volatile("s_waitcnt vmcnt(4)" ::: "memory");
    } else if (tt + 2 == nt) {
      asm volatile("s_waitcnt vmcnt(0)" ::: "memory");
    }
    BAR();
    __builtin_amdgcn_s_setprio(1);
    #pragma unroll
    for (int mi = 0; mi < 4; ++mi)
      #pragma unroll
      for (int ni = 0; ni < 4; ++ni)
        acc[mi+4][ni] = __builtin_amdgcn_mfma_f32_16x16x32_bf16(af[mi], bf[ni], acc[mi+4][ni], 0, 0, 0);
    __builtin_amdgcn_s_setprio(0);
    BAR();
  }
  #undef STAGE_A
  #undef STAGE_B

  const int crow = kq * 4;
  if (EPI == 1 && col0 >= 2048) {
    // V columns -> vt[b][h][d][2048] (u16); addr = (b<<21) + (h*64+d)*2048 + s
    const int hd0 = col0 - 2048 + wn*64 + mrow;
    #pragma unroll
    for (int mi = 0; mi < 8; ++mi) {
      #pragma unroll
      for (int r = 0; r < 4; ++r) {
        const int row = row0 + wm*128 + mi*16 + crow + r;
        const int bb = row >> 11, ss = row & 2047;
        uint16_t* vr = vt + ((size_t)bb << 21) + ss;
        #pragma unroll
        for (int ni = 0; ni < 4; ++ni)
          vr[(size_t)(hd0 + ni*16) << 11] = f2bf(acc[mi][ni][r]);
      }
    }
  } else {
    float bv[4];
    #pragma unroll
    for (int ni = 0; ni < 4; ++ni)
      bv[ni] = (EPI == 2) ? bias[col0 + wn*64 + ni*16 + mrow] : 0.0f;
    #pragma unroll
    for (int mi = 0; mi < 8; ++mi) {
      #pragma unroll
      for (int r = 0; r < 4; ++r) {
        const int row = row0 + wm*128 + mi*16 + crow + r;
        uint16_t* Cr = C + (size_t)row * N + col0 + wn*64 + mrow;
        #pragma unroll
        for (int ni = 0; ni < 4; ++ni) {
          float v = acc[mi][ni][r] + bv[ni];
          if (EPI == 2) v = gelu_f(v);
          Cr[ni*16] = f2bf(v);
        }
      }
    }
  }
}

// ===== 128x128 deep-pipelined GEMM: out = A @ Bm^T + bias + res (fp32) =====
__global__ __launch_bounds__(512, 2) void gemm128r(
    const uint16_t* __restrict__ A, const uint16_t* __restrict__ Bm,
    const float* __restrict__ bias, const float* __restrict__ res,
    float* __restrict__ out, int M, int N, int K)
{
  __shared__ __align__(16) uint16_t L[4 * 16384];   // 128 KB
  const int t = threadIdx.x;
  const int l = t & 63;
  const int w = t >> 6;
  const int wm = w >> 2, wn = w & 3;                // 2 x 4 wave grid
  const int row0 = blockIdx.x * 128, col0 = blockIdx.y * 128;
  const int mrow = l & 15, kq = l >> 4;
  const int nt = K >> 6;                            // K-tiles of 64

  f32x4 acc[4][2];
  #pragma unroll
  for (int i = 0; i < 4; ++i)
    #pragma unroll
    for (int j = 0; j < 2; ++j)
      #pragma unroll
      for (int e = 0; e < 4; ++e) acc[i][j][e] = 0.0f;

  const int sr = t >> 3;                            // row-in-half 0..63
  const int kl = (t & 7) ^ (sr & 7);                // swizzled global chunk
  const uint16_t* aG = A  + (size_t)(row0 + sr) * K + kl * 8;
  const uint16_t* bG = Bm + (size_t)(col0 + sr) * K + kl * 8;
  char* const lds = (char*)L;
  const int soff = t * 16;

  #define STAGE_A(tt_) { char* d_ = lds + ((tt_) & 3) * 32768 + soff; \
      gl_lds16(aG + (tt_) * 64, d_); \
      gl_lds16(aG + (size_t)64 * K + (tt_) * 64, d_ + 8192); }
  #define STAGE_B(tt_) { char* d_ = lds + ((tt_) & 3) * 32768 + 16384 + soff; \
      gl_lds16(bG + (tt_) * 64, d_); \
      gl_lds16(bG + (size_t)64 * K + (tt_) * 64, d_ + 8192); }

  STAGE_A(0); STAGE_B(0);
  STAGE_A(1); STAGE_B(1);
  STAGE_A(2); STAGE_B(2);
  asm volatile("s_waitcnt vmcnt(8)" ::: "memory");
  BAR();

  for (int tt = 0; tt < nt; ++tt) {
    char* const bufA = lds + (tt & 3) * 32768;
    char* const bufB = bufA + 16384;
    // ---------------- phase A: k-slice 0 ----------------
    {
      const int pa = (kq ^ (mrow & 7)) * 16;        // ks=0
      short8 af[4], bf[2];
      #pragma unroll
      for (int ni = 0; ni < 2; ++ni)
        bf[ni] = *(const short8*)(bufB + (wn*32 + ni*16 + mrow) * 128 + pa);
      #pragma unroll
      for (int mi = 0; mi < 4; ++mi)
        af[mi] = *(const short8*)(bufA + (wm*64 + mi*16 + mrow) * 128 + pa);
      if (tt + 3 < nt) STAGE_A(tt + 3);
      BAR();
      __builtin_amdgcn_s_setprio(1);
      #pragma unroll
      for (int mi = 0; mi < 4; ++mi)
        #pragma unroll
        for (int ni = 0; ni < 2; ++ni)
          acc[mi][ni] = __builtin_amdgcn_mfma_f32_16x16x32_bf16(af[mi], bf[ni], acc[mi][ni], 0, 0, 0);
      __builtin_amdgcn_s_setprio(0);
      BAR();
    }
    // ---------------- phase B: k-slice 1 ----------------
    {
      const int pa = ((4 + kq) ^ (mrow & 7)) * 16;  // ks=1
      short8 af[4], bf[2];
      #pragma unroll
      for (int ni = 0; ni < 2; ++ni)
        bf[ni] = *(const short8*)(bufB + (wn*32 + ni*16 + mrow) * 128 + pa);
      #pragma unroll
      for (int mi = 0; mi < 4; ++mi)
        af[mi] = *(const short8*)(bufA + (wm*64 + mi*16 + mrow) * 128 + pa);
      if (tt + 3 < nt) {
        STAGE_B(tt + 3);
        asm volatile("s_waitcnt vmcnt(8)" ::: "memory");   // tile tt+1 landed
      } else if (tt + 3 == nt) {
        asm volatile("s_waitcnt vmcnt(4)" ::: "memory");
      } else if (tt + 2 == nt) {
        asm volatile("s_waitcnt vmcnt(0)" ::: "memory");
      }
      BAR();
      __builtin_amdgcn_s_setprio(1);
      #pragma unroll
      for (int mi = 0; mi < 4; ++mi)
        #pragma unroll
        for (int ni = 0; ni < 2; ++ni)
          acc[mi][ni] = __builtin_amdgcn_mfma_f32_16x16x32_bf16(af[mi], bf[ni], acc[mi][ni], 0, 0, 0);
      __builtin_amdgcn_s_setprio(0);
      BAR();
    }
  }
  #undef STAGE_A
  #undef STAGE_B

  const int crow = kq * 4;
  float bv[2];
  #pragma unroll
  for (int ni = 0; ni < 2; ++ni)
    bv[ni] = bias[col0 + wn*32 + ni*16 + mrow];
  #pragma unroll
  for (int mi = 0; mi < 4; ++mi)
    #pragma unroll
    for (int r = 0; r < 4; ++r) {
      const int row = row0 + wm*64 + mi*16 + crow + r;
      const size_t base = (size_t)row * N + col0 + wn*32 + mrow;
      #pragma unroll
      for (int ni = 0; ni < 2; ++ni)
        out[base + ni*16] = acc[mi][ni][r] + bv[ni] + res[base + ni*16];
    }
}

// --------------------- local-window attention (MFMA) -----------------------
// V arrives PRE-TRANSPOSED (vt[b][h][d][2048], written by the QKV GEMM), so
// there is no in-kernel transpose. All operands staged chunk-major via
// global_load_lds: Qc[8c][32r], Kc[8c][288j], Vc[36c][64d] (16B chunks) ->
// every MFMA-fragment LDS read is 16 consecutive 16B slots = conflict-free.
// Ps (softmax out) overlays Kc after QK^T. LDS 76 KB -> 2 blocks/CU.
#define TQ    32
#define NKT   18
#define NKP   288
#define PSTR  296        // Ps row stride (bf16); 592 B -> 2-way on reads (free)

__global__ __launch_bounds__(256) void attn_kernel(const uint16_t* __restrict__ qkv,
                                                   const uint16_t* __restrict__ vtg,
                                                   uint16_t* __restrict__ out)
{
  __shared__ __align__(16) uint16_t Qc[8*32*8];     //  4 KB
  __shared__ __align__(16) uint16_t Kc[8*288*8];    // 36 KB (Ps overlays after QK^T)
  __shared__ __align__(16) uint16_t Vc[36*64*8];    // 36 KB
  const int t = threadIdx.x, l = t & 63, w = t >> 6;
  const int b = blockIdx.z, hh = blockIdx.y, q0 = blockIdx.x * TQ;
  const int k0 = (q0 - WIN > 0) ? (q0 - WIN) : 0;
  const int kend_ = q0 + TQ + WIN;
  const int kend = (kend_ < SEQ) ? kend_ : SEQ;
  const int nk = kend - k0;

  // ---- stage V^T, K, Q via global_load_lds (19 async loads/thread) ----
  {
    const size_t vbase = ((size_t)(b*NHEAD + hh) << 17);   // *64*2048
    #pragma unroll
    for (int i = 0; i < 9; ++i) {                          // V: slot = c*64+d
      const int s = i*256 + t;
      const int c = s >> 6, d = s & 63;
      int off = k0 + c*8; if (off > 2040) off = 2040;      // clamp (P=0 there)
      gl_lds16(vtg + vbase + ((size_t)d << 11) + off, (char*)Vc + (size_t)s*16);
    }
    #pragma unroll
    for (int i = 0; i < 9; ++i) {                          // K: slot = c*288+j
      const int s = i*256 + t;
      const int c = s / 288;
      const int j = s - c*288;
      const int js = (j < nk) ? j : (nk - 1);              // clamp (masked later)
      gl_lds16(qkv + (size_t)(b*SEQ + k0 + js)*3072 + 1024 + hh*64 + c*8,
               (char*)Kc + (size_t)s*16);
    }
    gl_lds16(qkv + (size_t)(b*SEQ + q0 + (t & 31))*3072 + hh*64 + (t >> 5)*8,
             (char*)Qc + (size_t)t*16);
  }
  __syncthreads();   // drains vmcnt(0): all operands staged

  const int mrow = l & 15, q4 = l >> 4;
  f32x4 cacc[NKT];
  if (w < 2) {
    // ---- QK^T (waves 0,1; 36 MFMA each) ----
    const int rb = w * 16;
    const short8 aq0 = *(const short8*)((const char*)Qc + (((q4    )*32 + rb + mrow) << 4));
    const short8 aq1 = *(const short8*)((const char*)Qc + (((4 + q4)*32 + rb + mrow) << 4));
    #pragma unroll
    for (int ct = 0; ct < NKT; ++ct) {
      f32x4 c; c[0]=0.f; c[1]=0.f; c[2]=0.f; c[3]=0.f;
      const short8 b0 = *(const short8*)((const char*)Kc + (((q4    )*288 + ct*16 + mrow) << 4));
      const short8 b1 = *(const short8*)((const char*)Kc + (((4 + q4)*288 + ct*16 + mrow) << 4));
      c = __builtin_amdgcn_mfma_f32_16x16x32_bf16(aq0, b0, c, 0, 0, 0);
      c = __builtin_amdgcn_mfma_f32_16x16x32_bf16(aq1, b1, c, 0, 0, 0);
      cacc[ct] = c;
    }
    // ---- softmax fully in registers (mask, max, exp, normalize) ----
    #pragma unroll
    for (int r = 0; r < 4; ++r) {
      const int iq = q0 + rb + q4*4 + r;
      float m = -1e30f;
      #pragma unroll
      for (int ct = 0; ct < NKT; ++ct) {
        const int jj = ct*16 + mrow;
        const int j = k0 + jj;
        const bool ok = (jj < nk) && (j >= iq - WIN) && (j <= iq + WIN);
        const float s = ok ? cacc[ct][r] * 0.125f : -1e30f;
        cacc[ct][r] = s;
        m = fmaxf(m, s);
      }
      m = fmaxf(m, __shfl_xor(m, 1, 64));
      m = fmaxf(m, __shfl_xor(m, 2, 64));
      m = fmaxf(m, __shfl_xor(m, 4, 64));
      m = fmaxf(m, __shfl_xor(m, 8, 64));
      float s = 0.f;
      #pragma unroll
      for (int ct = 0; ct < NKT; ++ct) {
        const float e = __expf(cacc[ct][r] - m);
        cacc[ct][r] = e;
        s += e;
      }
      s += __shfl_xor(s, 1, 64);
      s += __shfl_xor(s, 2, 64);
      s += __shfl_xor(s, 4, 64);
      s += __shfl_xor(s, 8, 64);
      const float rinv = 1.0f / s;
      #pragma unroll
      for (int ct = 0; ct < NKT; ++ct)
        cacc[ct][r] *= rinv;
    }
  }
  __syncthreads();   // all QK^T reads of Kc complete -> Ps may overlay

  if (w < 2) {
    uint16_t* Ps = Kc;
    const int rb = w * 16;
    #pragma unroll
    for (int r = 0; r < 4; ++r)
      #pragma unroll
      for (int ct = 0; ct < NKT; ++ct)
        Ps[(rb + q4*4 + r) * PSTR + ct*16 + mrow] = f2bf(cacc[ct][r]);
  }
  __syncthreads();

  // ---- PV: all 4 waves; b-frag from Vc is 16 consecutive slots ----
  {
    const uint16_t* Ps = Kc;
    const int rt = w & 1, dt0 = (w >> 1) * 2;
    f32x4 o0, o1;
    #pragma unroll
    for (int e = 0; e < 4; ++e) { o0[e] = 0.f; o1[e] = 0.f; }
    #pragma unroll
    for (int ks = 0; ks < 9; ++ks) {
      const short8 a  = *(const short8*)((const char*)Ps + (rt*16 + mrow)*(PSTR*2) + ks*64 + q4*16);
      const short8 v0 = *(const short8*)((const char*)Vc + (((ks*4 + q4)*64 + dt0*16 + mrow) << 4));
      const short8 v1 = *(const short8*)((const char*)Vc + (((ks*4 + q4)*64 + (dt0+1)*16 + mrow) << 4));
      o0 = __builtin_amdgcn_mfma_f32_16x16x32_bf16(a, v0, o0, 0, 0, 0);
      o1 = __builtin_amdgcn_mfma_f32_16x16x32_bf16(a, v1, o1, 0, 0, 0);
    }
    #pragma unroll
    for (int r = 0; r < 4; ++r) {
      const int iq = q0 + rt*16 + q4*4 + r;
      const size_t rowoff = (size_t)(b*SEQ + iq) * DMODEL + hh*64;
      out[rowoff + (dt0  )*16 + mrow] = f2bf(o0[r]);
      out[rowoff + (dt0+1)*16 + mrow] = f2bf(o1[r]);
    }
  }
}

// --------------------------------- launch ----------------------------------
extern "C" void kernel_launch(void* const* d_in, const int* in_sizes, int n_in,
                              void* d_out, int out_size, void* d_ws, size_t ws_size,
                              hipStream_t stream)
{
  const float* x    = (const float*)d_in[0];
  const float* ln1g = (const float*)d_in[1];
  const float* ln1b = (const float*)d_in[2];
  const float* wqkv = (const float*)d_in[3];
  const float* wout = (const float*)d_in[4];
  const float* bout = (const float*)d_in[5];
  const float* ln2g = (const float*)d_in[6];
  const float* ln2b = (const float*)d_in[7];
  const float* wff1 = (const float*)d_in[8];
  const float* bff1 = (const float*)d_in[9];
  const float* wff2 = (const float*)d_in[10];
  const float* bff2 = (const float*)d_in[11];
  float* out = (float*)d_out;

  char* ws = (char*)d_ws;
  const size_t MB = (size_t)1 << 20;
  uint16_t* Wqkv = (uint16_t*)(ws);            //  0-6
  uint16_t* Wout = (uint16_t*)(ws +  6*MB);    //  6-8
  uint16_t* Wff1 = (uint16_t*)(ws +  8*MB);    //  8-16
  uint16_t* Wff2 = (uint16_t*)(ws + 16*MB);    // 16-24
  uint16_t* QKV  = (uint16_t*)(ws + 24*MB);    // 24-48 (Q,K; V region unused)
  uint16_t* H1   = (uint16_t*)(ws + 48*MB);    // 48-56 h1 -> attn_out
  uint16_t* AT   = H1;
  float*    X2f  = (float*)   (ws + 56*MB);    // 56-72 fp32 (live to end)
  uint16_t* H2   = (uint16_t*)(ws + 72*MB);    // 72-80
  uint16_t* FF1  = (uint16_t*)(ws + 24*MB);    // 24-56 (qkv+attn dead)
  uint16_t* VT   = (uint16_t*)(ws + 80*MB);    // 80-88 V transposed [b][h][d][2048]
  // high-water: 88 MB (ws proven >= 97 MB by earlier diagnostic)

  // 1) weights fp32->bf16 + h1 = LN1(x)   (fused, 16384 blocks)
  cvtln_kernel<<<16384, 256, 0, stream>>>(wqkv, wout, wff1, wff2,
                                          Wqkv, Wout, Wff1, Wff2,
                                          x, ln1g, ln1b, H1);
  // 2) qkv = h1 @ w_qkv^T; V cols scattered transposed into VT
  gemm256<1><<<dim3(3072/256, MTOK/256), 512, 0, stream>>>(H1, Wqkv, nullptr, QKV, VT, MTOK, 3072, DMODEL);
  // 3) attn_out = local_attention(Q,K from QKV; V^T from VT)
  attn_kernel<<<dim3(SEQ/TQ, NHEAD, NB), 256, 0, stream>>>(QKV, VT, AT);
  // 4) x2 = attn_out @ w_out^T + b_out + x  (128^2 deep-pipelined)
  gemm128r<<<dim3(MTOK/128, DMODEL/128), 512, 0, stream>>>(AT, Wout, bout, x, X2f, MTOK, DMODEL, DMODEL);
  // 5) h2 = LN2(x2)
  ln_kernel<<<MTOK, 256, 0, stream>>>(X2f, ln2g, ln2b, H2);
  // 6) ff1 = gelu(h2 @ w_ff1^T + b_ff1)   (256^2 deep-pipelined)
  gemm256<2><<<dim3(FFDIM/256, MTOK/256), 512, 0, stream>>>(H2, Wff1, bff1, FF1, nullptr, MTOK, FFDIM, DMODEL);
  // 7) out = ff1 @ w_ff2^T + b_ff2 + x2   (128^2 deep-pipelined, K=4096)
  gemm128r<<<dim3(MTOK/128, DMODEL/128), 512, 0, stream>>>(FF1, Wff2, bff2, X2f, out, MTOK, DMODEL, FFDIM);
}

// Round 4
// 308.537 us; speedup vs baseline: 1.1102x; 1.0013x over previous
//
#include <hip/hip_runtime.h>
#include <stdint.h>

#define SEQ    2048
#define NB     2
#define DMODEL 1024
#define NHEAD  16
#define HDIM   64
#define FFDIM  4096
#define WIN    128
#define MTOK   (NB*SEQ)   // 4096 tokens

typedef short short8 __attribute__((ext_vector_type(8)));  // 8 bf16 (4 VGPRs)
typedef float f32x4  __attribute__((ext_vector_type(4)));

__device__ __forceinline__ float bf2f(uint16_t h){ return __uint_as_float(((uint32_t)h) << 16); }
__device__ __forceinline__ uint16_t f2bf(float f){           // RNE f32->bf16
  uint32_t u = __float_as_uint(f);
  u += 0x7fffu + ((u >> 16) & 1u);
  return (uint16_t)(u >> 16);
}

// tanh-form GELU, branch-free; max |delta| vs exact erf-GELU ~3e-3.
__device__ __forceinline__ float gelu_f(float v){
  float u = 0.7978845608028654f * v * (1.0f + 0.044715f * v * v);
  u = fminf(fmaxf(u, -10.0f), 10.0f);
  const float e = __expf(2.0f * u);
  const float th = (e - 1.0f) / (e + 1.0f);
  return 0.5f * v * (1.0f + th);
}

__device__ __forceinline__ void gl_lds16(const void* g, void* l) {
  __builtin_amdgcn_global_load_lds((const __attribute__((address_space(1))) void*)g,
                                   (__attribute__((address_space(3))) void*)l, 16, 0, 0);
}

// Raw workgroup barrier: NO memory-clobber asm (a "memory" clobber makes
// SIInsertWaitcnts emit a full vmcnt(0) drain before it, which defeats the
// counted-vmcnt pipeline). sched_barrier(0) pins instruction order across
// the barrier (prevents next-phase ds_read hoisting above it — rule #18).
__device__ __forceinline__ void BAR() {
  __builtin_amdgcn_s_barrier();
  __builtin_amdgcn_sched_barrier(0);
}

// ---- fused: weights fp32->bf16 (blocks 0..12287) + LN1 (blocks 12288..16383)
__global__ __launch_bounds__(256) void cvtln_kernel(
    const float* __restrict__ s0, const float* __restrict__ s1,
    const float* __restrict__ s2, const float* __restrict__ s3,
    uint16_t* __restrict__ d0, uint16_t* __restrict__ d1,
    uint16_t* __restrict__ d2, uint16_t* __restrict__ d3,
    const float* __restrict__ x, const float* __restrict__ g,
    const float* __restrict__ b, uint16_t* __restrict__ y)
{
  __shared__ float red[8];
  const int t = threadIdx.x;
  if (blockIdx.x < 12288) {
    size_t i = (size_t)blockIdx.x * 256 + t;   // float4 index; 3,145,728 total
    const float* s; uint16_t* d; size_t off;
    if      (i <  768*1024) { s = s0; d = d0; off = i; }
    else if (i < 1024*1024) { s = s1; d = d1; off = i -  768*1024; }
    else if (i < 2048*1024) { s = s2; d = d2; off = i - 1024*1024; }
    else                    { s = s3; d = d3; off = i - 2048*1024; }
    const float4 v = ((const float4*)s)[off];
    uint2 o;
    o.x = (uint32_t)f2bf(v.x) | ((uint32_t)f2bf(v.y) << 16);
    o.y = (uint32_t)f2bf(v.z) | ((uint32_t)f2bf(v.w) << 16);
    ((uint2*)d)[off] = o;
  } else {
    const int row = blockIdx.x - 12288;
    const float4 v = ((const float4*)(x + (size_t)row * DMODEL))[t];
    float s1 = v.x + v.y + v.z + v.w;
    float s2 = v.x*v.x + v.y*v.y + v.z*v.z + v.w*v.w;
    #pragma unroll
    for (int off = 32; off; off >>= 1) { s1 += __shfl_xor(s1, off, 64); s2 += __shfl_xor(s2, off, 64); }
    const int w = t >> 6;
    if ((t & 63) == 0) { red[w] = s1; red[4+w] = s2; }
    __syncthreads();
    s1 = red[0]+red[1]+red[2]+red[3];
    s2 = red[4]+red[5]+red[6]+red[7];
    const float mu = s1 * (1.0f/DMODEL);
    const float var = s2 * (1.0f/DMODEL) - mu*mu;
    const float rs = rsqrtf(var + 1e-5f);
    const float4 gv = ((const float4*)g)[t];
    const float4 bv = ((const float4*)b)[t];
    uint2 o;
    o.x = (uint32_t)f2bf((v.x-mu)*rs*gv.x + bv.x) | ((uint32_t)f2bf((v.y-mu)*rs*gv.y + bv.y) << 16);
    o.y = (uint32_t)f2bf((v.z-mu)*rs*gv.z + bv.z) | ((uint32_t)f2bf((v.w-mu)*rs*gv.w + bv.w) << 16);
    ((uint2*)(y + (size_t)row * DMODEL))[t] = o;
  }
}

// -------- LayerNorm: fp32 in -> bf16 out; one row (1024) per block ---------
__global__ __launch_bounds__(256) void ln_kernel(const float* __restrict__ x,
                                                 const float* __restrict__ g,
                                                 const float* __restrict__ b,
                                                 uint16_t* __restrict__ y)
{
  const int row = blockIdx.x;
  const int t = threadIdx.x;
  const float4 v = ((const float4*)(x + (size_t)row * DMODEL))[t];
  float s1 = v.x + v.y + v.z + v.w;
  float s2 = v.x*v.x + v.y*v.y + v.z*v.z + v.w*v.w;
  #pragma unroll
  for (int off = 32; off; off >>= 1) { s1 += __shfl_xor(s1, off, 64); s2 += __shfl_xor(s2, off, 64); }
  __shared__ float red[8];
  const int w = t >> 6;
  if ((t & 63) == 0) { red[w] = s1; red[4+w] = s2; }
  __syncthreads();
  s1 = red[0]+red[1]+red[2]+red[3];
  s2 = red[4]+red[5]+red[6]+red[7];
  const float mu = s1 * (1.0f/DMODEL);
  const float var = s2 * (1.0f/DMODEL) - mu*mu;
  const float rs = rsqrtf(var + 1e-5f);
  const float4 gv = ((const float4*)g)[t];
  const float4 bv = ((const float4*)b)[t];
  uint2 o;
  o.x = (uint32_t)f2bf((v.x-mu)*rs*gv.x + bv.x) | ((uint32_t)f2bf((v.y-mu)*rs*gv.y + bv.y) << 16);
  o.y = (uint32_t)f2bf((v.z-mu)*rs*gv.z + bv.z) | ((uint32_t)f2bf((v.w-mu)*rs*gv.w + bv.w) << 16);
  ((uint2*)(y + (size_t)row * DMODEL))[t] = o;
}

// ============ 256x256 deep-pipelined GEMM: C = A @ Bm^T (bf16 out) =========
// BK=32, 4-buffer LDS ring (128 KB), 512 thr / 8 waves, counted vmcnt(8)
// (bare asm, no clobber), raw s_barrier + sched_barrier(0), setprio.
// EPI: 0 = none; 1 = QKV (V-col blocks scatter to vt[b][h][d][2048]);
// EPI: 2 = bias + GELU.
template<int EPI>
__global__ __launch_bounds__(512, 2) void gemm256(
    const uint16_t* __restrict__ A, const uint16_t* __restrict__ Bm,
    const float* __restrict__ bias, uint16_t* __restrict__ C,
    uint16_t* __restrict__ vt, int M, int N, int K)
{
  __shared__ __align__(16) uint16_t L[4 * 16384];   // 128 KB
  const int t = threadIdx.x;
  const int l = t & 63;
  const int w = t >> 6;
  const int wm = w >> 2, wn = w & 3;                // 2 x 4 wave grid
  const int row0 = blockIdx.y * 256, col0 = blockIdx.x * 256;
  const int mrow = l & 15, kq = l >> 4;
  const int nt = K >> 5;                            // K-tiles of 32

  f32x4 acc[8][4];
  #pragma unroll
  for (int i = 0; i < 8; ++i)
    #pragma unroll
    for (int j = 0; j < 4; ++j)
      #pragma unroll
      for (int e = 0; e < 4; ++e) acc[i][j][e] = 0.0f;

  const int sr = t >> 2;                            // row-in-half 0..127
  const int kl = (t & 3) ^ ((t >> 3) & 3);          // logical k-chunk 0..3
  const uint16_t* aG = A  + (size_t)(row0 + sr) * K + kl * 8;
  const uint16_t* bG = Bm + (size_t)(col0 + sr) * K + kl * 8;
  char* const lds = (char*)L;
  const int soff = t * 16;

  #define STAGE_A(tt_) { char* d_ = lds + ((tt_) & 3) * 32768 + soff; \
      gl_lds16(aG + (tt_) * 32, d_); \
      gl_lds16(aG + (size_t)128 * K + (tt_) * 32, d_ + 8192); }
  #define STAGE_B(tt_) { char* d_ = lds + ((tt_) & 3) * 32768 + 16384 + soff; \
      gl_lds16(bG + (tt_) * 32, d_); \
      gl_lds16(bG + (size_t)128 * K + (tt_) * 32, d_ + 8192); }

  STAGE_A(0); STAGE_B(0);
  STAGE_A(1); STAGE_B(1);
  STAGE_A(2); STAGE_B(2);
  asm volatile("s_waitcnt vmcnt(8)");
  BAR();

  const int cphys = (kq ^ ((mrow >> 1) & 3)) << 4;  // physical chunk byte off

  for (int tt = 0; tt < nt; ++tt) {
    char* const bufA = lds + (tt & 3) * 32768;
    char* const bufB = bufA + 16384;
    // ---------------- phase A: mi 0..3 x ni 0..3 ----------------
    short8 bf[4], af[4];
    #pragma unroll
    for (int ni = 0; ni < 4; ++ni)
      bf[ni] = *(const short8*)(bufB + (wn*64 + ni*16 + mrow) * 64 + cphys);
    #pragma unroll
    for (int mi = 0; mi < 4; ++mi)
      af[mi] = *(const short8*)(bufA + (wm*128 + mi*16 + mrow) * 64 + cphys);
    if (tt + 3 < nt) STAGE_A(tt + 3);
    BAR();
    __builtin_amdgcn_s_setprio(1);
    #pragma unroll
    for (int mi = 0; mi < 4; ++mi)
      #pragma unroll
      for (int ni = 0; ni < 4; ++ni)
        acc[mi][ni] = __builtin_amdgcn_mfma_f32_16x16x32_bf16(af[mi], bf[ni], acc[mi][ni], 0, 0, 0);
    __builtin_amdgcn_s_setprio(0);
    BAR();
    // ---------------- phase B: mi 4..7 x ni 0..3 (bf reused) ----
    #pragma unroll
    for (int mi = 0; mi < 4; ++mi)
      af[mi] = *(const short8*)(bufA + (wm*128 + (mi+4)*16 + mrow) * 64 + cphys);
    if (tt + 3 < nt) {
      STAGE_B(tt + 3);
      asm volatile("s_waitcnt vmcnt(8)");   // tile tt+1 landed
    } else if (tt + 3 == nt) {
      asm volatile("s_waitcnt vmcnt(4)");
    } else if (tt + 2 == nt) {
      asm volatile("s_waitcnt vmcnt(0)");
    }
    BAR();
    __builtin_amdgcn_s_setprio(1);
    #pragma unroll
    for (int mi = 0; mi < 4; ++mi)
      #pragma unroll
      for (int ni = 0; ni < 4; ++ni)
        acc[mi+4][ni] = __builtin_amdgcn_mfma_f32_16x16x32_bf16(af[mi], bf[ni], acc[mi+4][ni], 0, 0, 0);
    __builtin_amdgcn_s_setprio(0);
    BAR();
  }
  #undef STAGE_A
  #undef STAGE_B

  const int crow = kq * 4;
  if (EPI == 1 && col0 >= 2048) {
    // V columns -> vt[b][h][d][2048] (u16); addr = (b<<21) + (h*64+d)*2048 + s
    const int hd0 = col0 - 2048 + wn*64 + mrow;
    #pragma unroll
    for (int mi = 0; mi < 8; ++mi) {
      #pragma unroll
      for (int r = 0; r < 4; ++r) {
        const int row = row0 + wm*128 + mi*16 + crow + r;
        const int bb = row >> 11, ss = row & 2047;
        uint16_t* vr = vt + ((size_t)bb << 21) + ss;
        #pragma unroll
        for (int ni = 0; ni < 4; ++ni)
          vr[(size_t)(hd0 + ni*16) << 11] = f2bf(acc[mi][ni][r]);
      }
    }
  } else {
    float bv[4];
    #pragma unroll
    for (int ni = 0; ni < 4; ++ni)
      bv[ni] = (EPI == 2) ? bias[col0 + wn*64 + ni*16 + mrow] : 0.0f;
    #pragma unroll
    for (int mi = 0; mi < 8; ++mi) {
      #pragma unroll
      for (int r = 0; r < 4; ++r) {
        const int row = row0 + wm*128 + mi*16 + crow + r;
        uint16_t* Cr = C + (size_t)row * N + col0 + wn*64 + mrow;
        #pragma unroll
        for (int ni = 0; ni < 4; ++ni) {
          float v = acc[mi][ni][r] + bv[ni];
          if (EPI == 2) v = gelu_f(v);
          Cr[ni*16] = f2bf(v);
        }
      }
    }
  }
}

// ===== 128x128 deep-pipelined GEMM: out = A @ Bm^T + bias + res (fp32) =====
__global__ __launch_bounds__(512, 2) void gemm128r(
    const uint16_t* __restrict__ A, const uint16_t* __restrict__ Bm,
    const float* __restrict__ bias, const float* __restrict__ res,
    float* __restrict__ out, int M, int N, int K)
{
  __shared__ __align__(16) uint16_t L[4 * 16384];   // 128 KB
  const int t = threadIdx.x;
  const int l = t & 63;
  const int w = t >> 6;
  const int wm = w >> 2, wn = w & 3;                // 2 x 4 wave grid
  const int row0 = blockIdx.x * 128, col0 = blockIdx.y * 128;
  const int mrow = l & 15, kq = l >> 4;
  const int nt = K >> 6;                            // K-tiles of 64

  f32x4 acc[4][2];
  #pragma unroll
  for (int i = 0; i < 4; ++i)
    #pragma unroll
    for (int j = 0; j < 2; ++j)
      #pragma unroll
      for (int e = 0; e < 4; ++e) acc[i][j][e] = 0.0f;

  const int sr = t >> 3;                            // row-in-half 0..63
  const int kl = (t & 7) ^ (sr & 7);                // swizzled global chunk
  const uint16_t* aG = A  + (size_t)(row0 + sr) * K + kl * 8;
  const uint16_t* bG = Bm + (size_t)(col0 + sr) * K + kl * 8;
  char* const lds = (char*)L;
  const int soff = t * 16;

  #define STAGE_A(tt_) { char* d_ = lds + ((tt_) & 3) * 32768 + soff; \
      gl_lds16(aG + (tt_) * 64, d_); \
      gl_lds16(aG + (size_t)64 * K + (tt_) * 64, d_ + 8192); }
  #define STAGE_B(tt_) { char* d_ = lds + ((tt_) & 3) * 32768 + 16384 + soff; \
      gl_lds16(bG + (tt_) * 64, d_); \
      gl_lds16(bG + (size_t)64 * K + (tt_) * 64, d_ + 8192); }

  STAGE_A(0); STAGE_B(0);
  STAGE_A(1); STAGE_B(1);
  STAGE_A(2); STAGE_B(2);
  asm volatile("s_waitcnt vmcnt(8)");
  BAR();

  for (int tt = 0; tt < nt; ++tt) {
    char* const bufA = lds + (tt & 3) * 32768;
    char* const bufB = bufA + 16384;
    // ---------------- phase A: k-slice 0 ----------------
    {
      const int pa = (kq ^ (mrow & 7)) * 16;        // ks=0
      short8 af[4], bf[2];
      #pragma unroll
      for (int ni = 0; ni < 2; ++ni)
        bf[ni] = *(const short8*)(bufB + (wn*32 + ni*16 + mrow) * 128 + pa);
      #pragma unroll
      for (int mi = 0; mi < 4; ++mi)
        af[mi] = *(const short8*)(bufA + (wm*64 + mi*16 + mrow) * 128 + pa);
      if (tt + 3 < nt) STAGE_A(tt + 3);
      BAR();
      __builtin_amdgcn_s_setprio(1);
      #pragma unroll
      for (int mi = 0; mi < 4; ++mi)
        #pragma unroll
        for (int ni = 0; ni < 2; ++ni)
          acc[mi][ni] = __builtin_amdgcn_mfma_f32_16x16x32_bf16(af[mi], bf[ni], acc[mi][ni], 0, 0, 0);
      __builtin_amdgcn_s_setprio(0);
      BAR();
    }
    // ---------------- phase B: k-slice 1 ----------------
    {
      const int pa = ((4 + kq) ^ (mrow & 7)) * 16;  // ks=1
      short8 af[4], bf[2];
      #pragma unroll
      for (int ni = 0; ni < 2; ++ni)
        bf[ni] = *(const short8*)(bufB + (wn*32 + ni*16 + mrow) * 128 + pa);
      #pragma unroll
      for (int mi = 0; mi < 4; ++mi)
        af[mi] = *(const short8*)(bufA + (wm*64 + mi*16 + mrow) * 128 + pa);
      if (tt + 3 < nt) {
        STAGE_B(tt + 3);
        asm volatile("s_waitcnt vmcnt(8)");   // tile tt+1 landed
      } else if (tt + 3 == nt) {
        asm volatile("s_waitcnt vmcnt(4)");
      } else if (tt + 2 == nt) {
        asm volatile("s_waitcnt vmcnt(0)");
      }
      BAR();
      __builtin_amdgcn_s_setprio(1);
      #pragma unroll
      for (int mi = 0; mi < 4; ++mi)
        #pragma unroll
        for (int ni = 0; ni < 2; ++ni)
          acc[mi][ni] = __builtin_amdgcn_mfma_f32_16x16x32_bf16(af[mi], bf[ni], acc[mi][ni], 0, 0, 0);
      __builtin_amdgcn_s_setprio(0);
      BAR();
    }
  }
  #undef STAGE_A
  #undef STAGE_B

  const int crow = kq * 4;
  float bv[2];
  #pragma unroll
  for (int ni = 0; ni < 2; ++ni)
    bv[ni] = bias[col0 + wn*32 + ni*16 + mrow];
  #pragma unroll
  for (int mi = 0; mi < 4; ++mi)
    #pragma unroll
    for (int r = 0; r < 4; ++r) {
      const int row = row0 + wm*64 + mi*16 + crow + r;
      const size_t base = (size_t)row * N + col0 + wn*32 + mrow;
      #pragma unroll
      for (int ni = 0; ni < 2; ++ni)
        out[base + ni*16] = acc[mi][ni][r] + bv[ni] + res[base + ni*16];
    }
}

// --------------------- local-window attention (MFMA) -----------------------
// V arrives PRE-TRANSPOSED (vt[b][h][d][2048], written by the QKV GEMM), so
// there is no in-kernel transpose. All operands staged chunk-major via
// global_load_lds: Qc[8c][32r], Kc[8c][288j], Vc[36c][64d] (16B chunks) ->
// every MFMA-fragment LDS read is 16 consecutive 16B slots = conflict-free.
// Ps (softmax out) overlays Kc after QK^T. LDS 76 KB -> 2 blocks/CU.
#define TQ    32
#define NKT   18
#define NKP   288
#define PSTR  296        // Ps row stride (bf16); 592 B -> 2-way on reads (free)

__global__ __launch_bounds__(256) void attn_kernel(const uint16_t* __restrict__ qkv,
                                                   const uint16_t* __restrict__ vtg,
                                                   uint16_t* __restrict__ out)
{
  __shared__ __align__(16) uint16_t Qc[8*32*8];     //  4 KB
  __shared__ __align__(16) uint16_t Kc[8*288*8];    // 36 KB (Ps overlays after QK^T)
  __shared__ __align__(16) uint16_t Vc[36*64*8];    // 36 KB
  const int t = threadIdx.x, l = t & 63, w = t >> 6;
  const int b = blockIdx.z, hh = blockIdx.y, q0 = blockIdx.x * TQ;
  const int k0 = (q0 - WIN > 0) ? (q0 - WIN) : 0;
  const int kend_ = q0 + TQ + WIN;
  const int kend = (kend_ < SEQ) ? kend_ : SEQ;
  const int nk = kend - k0;

  // ---- stage V^T, K, Q via global_load_lds (19 async loads/thread) ----
  {
    const size_t vbase = ((size_t)(b*NHEAD + hh) << 17);   // *64*2048
    #pragma unroll
    for (int i = 0; i < 9; ++i) {                          // V: slot = c*64+d
      const int s = i*256 + t;
      const int c = s >> 6, d = s & 63;
      int off = k0 + c*8; if (off > 2040) off = 2040;      // clamp (P=0 there)
      gl_lds16(vtg + vbase + ((size_t)d << 11) + off, (char*)Vc + (size_t)s*16);
    }
    #pragma unroll
    for (int i = 0; i < 9; ++i) {                          // K: slot = c*288+j
      const int s = i*256 + t;
      const int c = s / 288;
      const int j = s - c*288;
      const int js = (j < nk) ? j : (nk - 1);              // clamp (masked later)
      gl_lds16(qkv + (size_t)(b*SEQ + k0 + js)*3072 + 1024 + hh*64 + c*8,
               (char*)Kc + (size_t)s*16);
    }
    gl_lds16(qkv + (size_t)(b*SEQ + q0 + (t & 31))*3072 + hh*64 + (t >> 5)*8,
             (char*)Qc + (size_t)t*16);
  }
  __syncthreads();   // drains vmcnt(0): all operands staged

  const int mrow = l & 15, q4 = l >> 4;
  f32x4 cacc[NKT];
  if (w < 2) {
    // ---- QK^T (waves 0,1; 36 MFMA each) ----
    const int rb = w * 16;
    const short8 aq0 = *(const short8*)((const char*)Qc + (((q4    )*32 + rb + mrow) << 4));
    const short8 aq1 = *(const short8*)((const char*)Qc + (((4 + q4)*32 + rb + mrow) << 4));
    #pragma unroll
    for (int ct = 0; ct < NKT; ++ct) {
      f32x4 c; c[0]=0.f; c[1]=0.f; c[2]=0.f; c[3]=0.f;
      const short8 b0 = *(const short8*)((const char*)Kc + (((q4    )*288 + ct*16 + mrow) << 4));
      const short8 b1 = *(const short8*)((const char*)Kc + (((4 + q4)*288 + ct*16 + mrow) << 4));
      c = __builtin_amdgcn_mfma_f32_16x16x32_bf16(aq0, b0, c, 0, 0, 0);
      c = __builtin_amdgcn_mfma_f32_16x16x32_bf16(aq1, b1, c, 0, 0, 0);
      cacc[ct] = c;
    }
    // ---- softmax fully in registers (mask, max, exp, normalize) ----
    #pragma unroll
    for (int r = 0; r < 4; ++r) {
      const int iq = q0 + rb + q4*4 + r;
      float m = -1e30f;
      #pragma unroll
      for (int ct = 0; ct < NKT; ++ct) {
        const int jj = ct*16 + mrow;
        const int j = k0 + jj;
        const bool ok = (jj < nk) && (j >= iq - WIN) && (j <= iq + WIN);
        const float s = ok ? cacc[ct][r] * 0.125f : -1e30f;
        cacc[ct][r] = s;
        m = fmaxf(m, s);
      }
      m = fmaxf(m, __shfl_xor(m, 1, 64));
      m = fmaxf(m, __shfl_xor(m, 2, 64));
      m = fmaxf(m, __shfl_xor(m, 4, 64));
      m = fmaxf(m, __shfl_xor(m, 8, 64));
      float s = 0.f;
      #pragma unroll
      for (int ct = 0; ct < NKT; ++ct) {
        const float e = __expf(cacc[ct][r] - m);
        cacc[ct][r] = e;
        s += e;
      }
      s += __shfl_xor(s, 1, 64);
      s += __shfl_xor(s, 2, 64);
      s += __shfl_xor(s, 4, 64);
      s += __shfl_xor(s, 8, 64);
      const float rinv = 1.0f / s;
      #pragma unroll
      for (int ct = 0; ct < NKT; ++ct)
        cacc[ct][r] *= rinv;
    }
  }
  __syncthreads();   // all QK^T reads of Kc complete -> Ps may overlay

  if (w < 2) {
    uint16_t* Ps = Kc;
    const int rb = w * 16;
    #pragma unroll
    for (int r = 0; r < 4; ++r)
      #pragma unroll
      for (int ct = 0; ct < NKT; ++ct)
        Ps[(rb + q4*4 + r) * PSTR + ct*16 + mrow] = f2bf(cacc[ct][r]);
  }
  __syncthreads();

  // ---- PV: all 4 waves; b-frag from Vc is 16 consecutive slots ----
  {
    const uint16_t* Ps = Kc;
    const int rt = w & 1, dt0 = (w >> 1) * 2;
    f32x4 o0, o1;
    #pragma unroll
    for (int e = 0; e < 4; ++e) { o0[e] = 0.f; o1[e] = 0.f; }
    #pragma unroll
    for (int ks = 0; ks < 9; ++ks) {
      const short8 a  = *(const short8*)((const char*)Ps + (rt*16 + mrow)*(PSTR*2) + ks*64 + q4*16);
      const short8 v0 = *(const short8*)((const char*)Vc + (((ks*4 + q4)*64 + dt0*16 + mrow) << 4));
      const short8 v1 = *(const short8*)((const char*)Vc + (((ks*4 + q4)*64 + (dt0+1)*16 + mrow) << 4));
      o0 = __builtin_amdgcn_mfma_f32_16x16x32_bf16(a, v0, o0, 0, 0, 0);
      o1 = __builtin_amdgcn_mfma_f32_16x16x32_bf16(a, v1, o1, 0, 0, 0);
    }
    #pragma unroll
    for (int r = 0; r < 4; ++r) {
      const int iq = q0 + rt*16 + q4*4 + r;
      const size_t rowoff = (size_t)(b*SEQ + iq) * DMODEL + hh*64;
      out[rowoff + (dt0  )*16 + mrow] = f2bf(o0[r]);
      out[rowoff + (dt0+1)*16 + mrow] = f2bf(o1[r]);
    }
  }
}

// --------------------------------- launch ----------------------------------
extern "C" void kernel_launch(void* const* d_in, const int* in_sizes, int n_in,
                              void* d_out, int out_size, void* d_ws, size_t ws_size,
                              hipStream_t stream)
{
  const float* x    = (const float*)d_in[0];
  const float* ln1g = (const float*)d_in[1];
  const float* ln1b = (const float*)d_in[2];
  const float* wqkv = (const float*)d_in[3];
  const float* wout = (const float*)d_in[4];
  const float* bout = (const float*)d_in[5];
  const float* ln2g = (const float*)d_in[6];
  const float* ln2b = (const float*)d_in[7];
  const float* wff1 = (const float*)d_in[8];
  const float* bff1 = (const float*)d_in[9];
  const float* wff2 = (const float*)d_in[10];
  const float* bff2 = (const float*)d_in[11];
  float* out = (float*)d_out;

  char* ws = (char*)d_ws;
  const size_t MB = (size_t)1 << 20;
  uint16_t* Wqkv = (uint16_t*)(ws);            //  0-6
  uint16_t* Wout = (uint16_t*)(ws +  6*MB);    //  6-8
  uint16_t* Wff1 = (uint16_t*)(ws +  8*MB);    //  8-16
  uint16_t* Wff2 = (uint16_t*)(ws + 16*MB);    // 16-24
  uint16_t* QKV  = (uint16_t*)(ws + 24*MB);    // 24-48 (Q,K; V region unused)
  uint16_t* H1   = (uint16_t*)(ws + 48*MB);    // 48-56 h1 -> attn_out
  uint16_t* AT   = H1;
  float*    X2f  = (float*)   (ws + 56*MB);    // 56-72 fp32 (live to end)
  uint16_t* H2   = (uint16_t*)(ws + 72*MB);    // 72-80
  uint16_t* FF1  = (uint16_t*)(ws + 24*MB);    // 24-56 (qkv+attn dead)
  uint16_t* VT   = (uint16_t*)(ws + 80*MB);    // 80-88 V transposed [b][h][d][2048]
  // high-water: 88 MB (ws proven >= 97 MB by earlier diagnostic)

  // 1) weights fp32->bf16 + h1 = LN1(x)   (fused, 16384 blocks)
  cvtln_kernel<<<16384, 256, 0, stream>>>(wqkv, wout, wff1, wff2,
                                          Wqkv, Wout, Wff1, Wff2,
                                          x, ln1g, ln1b, H1);
  // 2) qkv = h1 @ w_qkv^T; V cols scattered transposed into VT
  gemm256<1><<<dim3(3072/256, MTOK/256), 512, 0, stream>>>(H1, Wqkv, nullptr, QKV, VT, MTOK, 3072, DMODEL);
  // 3) attn_out = local_attention(Q,K from QKV; V^T from VT)
  attn_kernel<<<dim3(SEQ/TQ, NHEAD, NB), 256, 0, stream>>>(QKV, VT, AT);
  // 4) x2 = attn_out @ w_out^T + b_out + x  (128^2 deep-pipelined)
  gemm128r<<<dim3(MTOK/128, DMODEL/128), 512, 0, stream>>>(AT, Wout, bout, x, X2f, MTOK, DMODEL, DMODEL);
  // 5) h2 = LN2(x2)
  ln_kernel<<<MTOK, 256, 0, stream>>>(X2f, ln2g, ln2b, H2);
  // 6) ff1 = gelu(h2 @ w_ff1^T + b_ff1)   (256^2 deep-pipelined)
  gemm256<2><<<dim3(FFDIM/256, MTOK/256), 512, 0, stream>>>(H2, Wff1, bff1, FF1, nullptr, MTOK, FFDIM, DMODEL);
  // 7) out = ff1 @ w_ff2^T + b_ff2 + x2   (128^2 deep-pipelined, K=4096)
  gemm128r<<<dim3(MTOK/128, DMODEL/128), 512, 0, stream>>>(FF1, Wff2, bff2, X2f, out, MTOK, DMODEL, FFDIM);
}